// Round 28
// baseline (89.135 us; speedup 1.0000x reference)
//
#include <hip/hip_runtime.h>
#include <math.h>

#define NATOMS 10000
#define NEDGES 200000
#define NBINS  40000   // (receiver, species) bins = NATOMS*4
#define SCAN_BLOCKS 40 // 40*1024 >= NBINS

// CSR sorted by (receiver, species). Per-edge 60 bf16 values live only in LDS.
// T tile per atom: 256 bf16 (4 species x 64 PADDED slots), stored as 128 uints.
// word k of species s = slots (2k, 2k+1); slot order l0@0, l1@8, l2@28, l3@48;
// pads at 26,27,62,63 (zeroed). even slot -> low 16 bits.
// W2p layout: 80 rows x 64 float2; row = lbase + s*Nl + n, lbase l0@0,l1@32,l2@56,l3@72.
// float2 = (channel j, channel j+64) for lane j.

__device__ __forceinline__ unsigned short f2bf(float f) {
    unsigned int u = __float_as_uint(f);
    u += 0x7FFFu + ((u >> 16) & 1u);   // round-to-nearest-even
    return (unsigned short)(u >> 16);
}

__device__ __forceinline__ float bf2f(unsigned short h) {
    return __uint_as_float(((unsigned int)h) << 16);
}

// unpack slot idx from a 32-word bf16 species row (LDS or global)
__device__ __forceinline__ float tval(const unsigned int* ts, int idx) {
    unsigned int u = ts[idx >> 1];
    return __uint_as_float((idx & 1) ? (u & 0xFFFF0000u) : (u << 16));
}

// Parallel zero of counts (the runtime's fillBuffer uses a tiny grid -> 40us).
__global__ __launch_bounds__(1024) void zero_counts_kernel(int* __restrict__ counts)
{
    int i = blockIdx.x * 1024 + threadIdx.x;
    if (i < NBINS) counts[i] = 0;
}

// blocks [0,40): prep W2p (10240 elems, float2-pair layout). rest: count edges.
__global__ __launch_bounds__(256) void prep_count_kernel(
    const float* __restrict__ emb,
    const float* __restrict__ wm0, const float* __restrict__ wm1,
    const float* __restrict__ wm2, const float* __restrict__ wm3,
    float* __restrict__ W2p,
    const int* __restrict__ receivers, const int* __restrict__ senders,
    const int* __restrict__ species, int* __restrict__ counts)
{
    if (blockIdx.x < 40) {
        int tid = blockIdx.x * 256 + threadIdx.x;
        if (tid >= 10240) return;
        const float* wm; int idx, Nl, lbase;
        if (tid < 4096)      { wm = wm0; idx = tid;        Nl = 8; lbase = 0;  }
        else if (tid < 7168) { wm = wm1; idx = tid - 4096; Nl = 6; lbase = 32; }
        else if (tid < 9216) { wm = wm2; idx = tid - 7168; Nl = 4; lbase = 56; }
        else                 { wm = wm3; idx = tid - 9216; Nl = 2; lbase = 72; }
        int j  = idx & 127;
        int sn = idx >> 7;
        int n  = sn % Nl;
        float acc = 0.0f;
        #pragma unroll
        for (int c = 0; c < 16; ++c)
            acc = fmaf(wm[(n*16 + c)*128 + j], emb[(sn / Nl)*16 + c], acc);
        int row = lbase + sn;
        W2p[(row*64 + (j & 63))*2 + (j >> 6)] = acc;
    } else {
        int e = (blockIdx.x - 40) * 256 + threadIdx.x;
        if (e < NEDGES) {
            int key = receivers[e] * 4 + species[senders[e]];
            atomicAdd(&counts[key], 1);
        }
    }
}

__global__ __launch_bounds__(1024) void scan1_kernel(
    const int* __restrict__ counts, int* __restrict__ offsets,
    int* __restrict__ blocksums)
{
    __shared__ int sh[1024];
    const int t = threadIdx.x;
    const int idx = blockIdx.x * 1024 + t;
    const int v = (idx < NBINS) ? counts[idx] : 0;
    sh[t] = v;
    __syncthreads();
    for (int off = 1; off < 1024; off <<= 1) {
        int u = (t >= off) ? sh[t - off] : 0;
        __syncthreads();
        sh[t] += u;
        __syncthreads();
    }
    if (idx < NBINS) offsets[idx] = sh[t] - v;   // block-local exclusive
    if (t == 1023) blocksums[blockIdx.x] = sh[1023];
}

// scan2 folded in: each block sums blocksums[0..bid) itself.
__global__ __launch_bounds__(1024) void scan3_kernel(
    int* __restrict__ offsets, int* __restrict__ cursor,
    const int* __restrict__ blocksums)
{
    __shared__ int sbase;
    if (threadIdx.x == 0) {
        int b = 0;
        for (int k = 0; k < (int)blockIdx.x; ++k) b += blocksums[k];
        sbase = b;
    }
    __syncthreads();
    const int idx = blockIdx.x * 1024 + threadIdx.x;
    if (idx < NBINS) {
        int o = offsets[idx] + sbase;
        offsets[idx] = o;
        cursor[idx]  = o;
    }
    if (idx == 0) offsets[NBINS] = NEDGES;
}

__global__ __launch_bounds__(256) void scatter_kernel(
    const int* __restrict__ receivers, const int* __restrict__ senders,
    const int* __restrict__ species, int* __restrict__ cursor,
    int* __restrict__ csr)
{
    int e = blockIdx.x * 256 + threadIdx.x;
    if (e < NEDGES) {
        int key = receivers[e] * 4 + species[senders[e]];
        int p = atomicAdd(&cursor[key], 1);
        csr[p] = e;
    }
}

// FUSED edge-math + T-build. 625 blocks x 256 threads; block owns 16 atoms.
// Output T is packed bf16 (128 uints/atom) via in-LDS staging transpose.
__global__ __launch_bounds__(256) void edge_tbuild_kernel(
    const float* __restrict__ pos,
    const float* __restrict__ wr0, const float* __restrict__ wr1,
    const float* __restrict__ wr2, const float* __restrict__ wr3,
    const int* __restrict__ senders,
    const int* __restrict__ receivers,
    const int* __restrict__ csr,
    const int* __restrict__ off4,
    unsigned int* __restrict__ Tb)
{
    const int tid  = threadIdx.x;
    const int w    = tid >> 6;
    const int lane = tid & 63;
    const int atomBase = blockIdx.x * 16;
    __shared__ unsigned int raw32[256 * 31];   // 31744 B, stride-31 rows

    int bnd[4][5];
    #pragma unroll
    for (int a = 0; a < 4; ++a)
        #pragma unroll
        for (int s = 0; s < 5; ++s)
            bnd[a][s] = off4[(atomBase + w*4 + a)*4 + s];
    const int blockBeg = off4[atomBase*4];
    const int blockEnd = off4[atomBase*4 + 64];

    float acc[4][4];
    #pragma unroll
    for (int a = 0; a < 4; ++a)
        #pragma unroll
        for (int s = 0; s < 4; ++s) acc[a][s] = 0.0f;

    const int dw   = lane >> 1;            // dword 0..29 (lanes 0..59)
    const int half = lane & 1;

    for (int c = blockBeg; c < blockEnd; c += 256) {
        const int i = c + tid;
        if (i < blockEnd) {
            const int e   = csr[i];
            const int snd = senders[e];
            const int rcv = receivers[e];

            float dx = pos[rcv*3]   - pos[snd*3];
            float dy = pos[rcv*3+1] - pos[snd*3+1];
            float dz = pos[rcv*3+2] - pos[snd*3+2];
            float r = sqrtf(dx*dx + dy*dy + dz*dz + 1e-12f);
            float inv_r = 1.0f / r;
            float x = dx * inv_r, y = dy * inv_r, z = dz * inv_r;

            float xr = fminf(r * 0.2f, 1.0f);
            float s1, c1;
            sincosf(3.14159265358979323846f * xr, &s1, &c1);
            float fcut = 0.5f * (c1 + 1.0f);
            float g = fcut / (xr + 0.001f);

            float bess[8];
            {
                float sm1 = 0.0f, s0 = s1;
                float tc = 2.0f * c1;
                #pragma unroll
                for (int n = 0; n < 8; ++n) {
                    bess[n] = s0 * g;
                    float s2 = tc * s0 - sm1;
                    sm1 = s0; s0 = s2;
                }
            }

            float R0[8], R1[6], R2[4], R3[2];
            #pragma unroll
            for (int n = 0; n < 8; ++n) R0[n] = 0.0f;
            #pragma unroll
            for (int n = 0; n < 6; ++n) R1[n] = 0.0f;
            #pragma unroll
            for (int n = 0; n < 4; ++n) R2[n] = 0.0f;
            #pragma unroll
            for (int n = 0; n < 2; ++n) R3[n] = 0.0f;
            #pragma unroll
            for (int k = 0; k < 8; ++k) {
                float b = bess[k];
                #pragma unroll
                for (int n = 0; n < 8; ++n) R0[n] = fmaf(b, wr0[k*8 + n], R0[n]);
                #pragma unroll
                for (int n = 0; n < 6; ++n) R1[n] = fmaf(b, wr1[k*6 + n], R1[n]);
                #pragma unroll
                for (int n = 0; n < 4; ++n) R2[n] = fmaf(b, wr2[k*4 + n], R2[n]);
                #pragma unroll
                for (int n = 0; n < 2; ++n) R3[n] = fmaf(b, wr3[k*2 + n], R3[n]);
            }

            float xy = x*y, yz = y*z, xz = x*z;
            float x2 = x*x, y2 = y*y, z2 = z*z;
            float sh1v[3] = {0.4886025119029199f*y, 0.4886025119029199f*z, 0.4886025119029199f*x};
            float sh2v[5] = {1.0925484305920792f*xy, 1.0925484305920792f*yz,
                             0.31539156525252005f*(3.0f*z2 - 1.0f),
                             1.0925484305920792f*xz, 0.5462742152960396f*(x2 - y2)};
            float sh3v[7] = {0.5900435899266435f*y*(3.0f*x2 - y2),
                             2.890611442640554f*xy*z,
                             0.4570457994644658f*y*(5.0f*z2 - 1.0f),
                             0.3731763325901154f*z*(5.0f*z2 - 3.0f),
                             0.4570457994644658f*x*(5.0f*z2 - 1.0f),
                             1.445305721320277f*z*(x2 - y2),
                             0.5900435899266435f*x*(x2 - 3.0f*y2)};

            unsigned short h[60];
            #pragma unroll
            for (int n = 0; n < 8; ++n)
                h[n] = f2bf(R0[n] * 0.28209479177387814f);
            #pragma unroll
            for (int n = 0; n < 6; ++n)
                #pragma unroll
                for (int m = 0; m < 3; ++m)
                    h[8 + n*3 + m] = f2bf(R1[n] * sh1v[m]);
            #pragma unroll
            for (int n = 0; n < 4; ++n)
                #pragma unroll
                for (int m = 0; m < 5; ++m)
                    h[26 + n*5 + m] = f2bf(R2[n] * sh2v[m]);
            #pragma unroll
            for (int n = 0; n < 2; ++n)
                #pragma unroll
                for (int m = 0; m < 7; ++m)
                    h[46 + n*7 + m] = f2bf(R3[n] * sh3v[m]);

            unsigned int* dst = &raw32[tid * 31];
            #pragma unroll
            for (int k = 0; k < 30; ++k)
                dst[k] = (unsigned int)h[2*k] | ((unsigned int)h[2*k+1] << 16);
        }
        __syncthreads();

        const int n = (blockEnd - c < 256) ? (blockEnd - c) : 256;
        if (lane < 60) {
            #pragma unroll
            for (int a = 0; a < 4; ++a) {
                #pragma unroll
                for (int s = 0; s < 4; ++s) {
                    const int lo = (bnd[a][s]   > c     ? bnd[a][s]   : c)     - c;
                    const int hi = (bnd[a][s+1] < c + n ? bnd[a][s+1] : c + n) - c;
                    float v = acc[a][s];
                    for (int r = lo; r < hi; ++r) {
                        unsigned int u = raw32[r*31 + dw];
                        v += bf2f(half ? (unsigned short)(u >> 16)
                                       : (unsigned short)(u & 0xFFFFu));
                    }
                    acc[a][s] = v;
                }
            }
        }
        __syncthreads();   // before next chunk overwrites raw32
    }

    // ---- pack T to bf16 via LDS staging (reuse raw32 as float stage) ----
    float* stageF = (float*)raw32;   // [w][a][s][64] floats = 16 KB
    const int pl = lane + (lane >= 26 ? 2 : 0);   // packed->padded
    if (lane < 60) {
        #pragma unroll
        for (int a = 0; a < 4; ++a)
            #pragma unroll
            for (int s = 0; s < 4; ++s)
                stageF[(((w*4 + a)*4 + s) << 6) + pl] = acc[a][s];
    } else {
        int p = lane - 60;
        int pi = (p < 2) ? (26 + p) : (62 + (p - 2));
        #pragma unroll
        for (int a = 0; a < 4; ++a)
            #pragma unroll
            for (int s = 0; s < 4; ++s)
                stageF[(((w*4 + a)*4 + s) << 6) + pi] = 0.0f;
    }
    __syncthreads();

    const int wi = lane & 31;        // word index within species row
    const int sh = lane >> 5;        // 0/1
    #pragma unroll
    for (int a = 0; a < 4; ++a) {
        const int atom = atomBase + w*4 + a;
        #pragma unroll
        for (int pass = 0; pass < 2; ++pass) {
            const int s = sh + pass*2;
            const float* src = &stageF[(((w*4 + a)*4 + s) << 6)];
            unsigned int word = (unsigned int)f2bf(src[2*wi])
                              | ((unsigned int)f2bf(src[2*wi + 1]) << 16);
            Tb[(size_t)atom*128 + s*32 + wi] = word;
        }
    }
}

// 250 blocks x 512 threads (8 waves). PURE-DS inner loop (r20 proven);
// epilogue writes peratom[] with a plain store (no contended atomics).
__global__ __launch_bounds__(512) void mix_kernel(
    const unsigned int* __restrict__ Tb,
    const float* __restrict__ W2p,
    const float* __restrict__ emb2,
    const float* __restrict__ w_out,
    const float* __restrict__ comp_weights,
    const float* __restrict__ scaling,
    const int* __restrict__ species,
    float* __restrict__ peratom)
{
    const int tid  = threadIdx.x;
    const int w    = tid >> 6;
    const int lane = tid & 63;
    __shared__ float2 Wl[5120];        // 80 rows x 64 lanes, 40 KB
    __shared__ unsigned int TlS[5120]; // 40 atoms x 128 words, 20 KB

    const float2* Wg = (const float2*)W2p;
    #pragma unroll
    for (int k = 0; k < 10; ++k) Wl[k*512 + tid] = Wg[k*512 + tid];
    const unsigned int* Tsrc = Tb + (size_t)blockIdx.x * 40 * 128;
    #pragma unroll
    for (int k = 0; k < 10; ++k) TlS[k*512 + tid] = Tsrc[k*512 + tid];
    __syncthreads();

    const float scal = scaling[0];
    const int atom0 = blockIdx.x * 40 + w * 5;

    #pragma unroll 1
    for (int i = 0; i < 5; ++i) {
        const int atom = atom0 + i;
        const unsigned int* tb = &TlS[(w*5 + i) * 128];

        float aa0_0 = 0.f, aa0_1 = 0.f;
        float b1_0[3] = {0.f,0.f,0.f},           b1_1[3] = {0.f,0.f,0.f};
        float b2_0[5] = {0.f,0.f,0.f,0.f,0.f},   b2_1[5] = {0.f,0.f,0.f,0.f,0.f};
        float b3_0[7] = {0.f,0.f,0.f,0.f,0.f,0.f,0.f};
        float b3_1[7] = {0.f,0.f,0.f,0.f,0.f,0.f,0.f};

        #pragma unroll
        for (int s = 0; s < 4; ++s) {
            const unsigned int* ts = tb + s * 32;   // LDS, uniform addr -> broadcast
            #pragma unroll
            for (int n = 0; n < 8; ++n) {
                float tv = tval(ts, n);
                float2 wv = Wl[(s*8+n)*64 + lane];
                aa0_0 = fmaf(wv.x, tv, aa0_0);
                aa0_1 = fmaf(wv.y, tv, aa0_1);
            }
            #pragma unroll
            for (int n = 0; n < 6; ++n) {
                float2 wv = Wl[(32 + s*6+n)*64 + lane];
                #pragma unroll
                for (int m = 0; m < 3; ++m) {
                    float tv = tval(ts, 8 + n*3 + m);
                    b1_0[m] = fmaf(wv.x, tv, b1_0[m]);
                    b1_1[m] = fmaf(wv.y, tv, b1_1[m]);
                }
            }
            #pragma unroll
            for (int n = 0; n < 4; ++n) {
                float2 wv = Wl[(56 + s*4+n)*64 + lane];
                #pragma unroll
                for (int m = 0; m < 5; ++m) {
                    float tv = tval(ts, 28 + n*5 + m);
                    b2_0[m] = fmaf(wv.x, tv, b2_0[m]);
                    b2_1[m] = fmaf(wv.y, tv, b2_1[m]);
                }
            }
            #pragma unroll
            for (int n = 0; n < 2; ++n) {
                float2 wv = Wl[(72 + s*2+n)*64 + lane];
                #pragma unroll
                for (int m = 0; m < 7; ++m) {
                    float tv = tval(ts, 48 + n*7 + m);
                    b3_0[m] = fmaf(wv.x, tv, b3_0[m]);
                    b3_1[m] = fmaf(wv.y, tv, b3_1[m]);
                }
            }
        }

        float Bj0 = aa0_0 * aa0_0;
        float Bj1 = aa0_1 * aa0_1;
        Bj0 += (b1_0[0]*b1_0[0] + b1_0[1]*b1_0[1] + b1_0[2]*b1_0[2]) * 0.57735026918962576f;
        Bj1 += (b1_1[0]*b1_1[0] + b1_1[1]*b1_1[1] + b1_1[2]*b1_1[2]) * 0.57735026918962576f;
        {
            float s0 = 0.f, s1v = 0.f;
            #pragma unroll
            for (int m = 0; m < 5; ++m) { s0 = fmaf(b2_0[m], b2_0[m], s0); s1v = fmaf(b2_1[m], b2_1[m], s1v); }
            Bj0 += s0 * 0.44721359549995794f;
            Bj1 += s1v * 0.44721359549995794f;
        }
        {
            float s0 = 0.f, s1v = 0.f;
            #pragma unroll
            for (int m = 0; m < 7; ++m) { s0 = fmaf(b3_0[m], b3_0[m], s0); s1v = fmaf(b3_1[m], b3_1[m], s1v); }
            Bj0 += s0 * 0.37796447300922725f;
            Bj1 += s1v * 0.37796447300922725f;
        }

        const int sp = species[atom];
        float v = Bj0 * Bj0 * emb2[sp*128 + lane] * w_out[lane]
                + Bj1 * Bj1 * emb2[sp*128 + lane + 64] * w_out[lane + 64];

        #pragma unroll
        for (int o = 32; o > 0; o >>= 1) v += __shfl_down(v, o, 64);
        if (lane == 0)
            peratom[atom] = fmaf(v, scal, comp_weights[sp]);   // plain store
    }
}

// SINGLE block: grid-stride peratom into LDS partials, then PLAIN STORE to
// out (no prior zeroing of d_out needed, no global atomics).
__global__ __launch_bounds__(1024) void outsum_kernel(
    const float* __restrict__ peratom,
    const int* __restrict__ batch_seg,
    float* __restrict__ out, int out_size)
{
    __shared__ float sacc[128];
    const int t = threadIdx.x;
    if (t < 128) sacc[t] = 0.0f;
    __syncthreads();
    for (int i = t; i < NATOMS; i += 1024)
        atomicAdd(&sacc[batch_seg[i]], peratom[i]);
    __syncthreads();
    if (t < out_size) out[t] = sacc[t];
}

extern "C" void kernel_launch(void* const* d_in, const int* in_sizes, int n_in,
                              void* d_out, int out_size, void* d_ws, size_t ws_size,
                              hipStream_t stream)
{
    const float* pos  = (const float*)d_in[0];
    const float* emb  = (const float*)d_in[1];
    const float* wr0  = (const float*)d_in[2];
    const float* wm0  = (const float*)d_in[3];
    const float* wr1  = (const float*)d_in[4];
    const float* wm1  = (const float*)d_in[5];
    const float* wr2  = (const float*)d_in[6];
    const float* wm2  = (const float*)d_in[7];
    const float* wr3  = (const float*)d_in[8];
    const float* wm3  = (const float*)d_in[9];
    const float* emb2 = (const float*)d_in[10];
    const float* wout = (const float*)d_in[11];
    const float* cw   = (const float*)d_in[12];
    const float* scal = (const float*)d_in[13];
    const int* species   = (const int*)d_in[14];
    const int* senders   = (const int*)d_in[15];
    const int* receivers = (const int*)d_in[16];
    const int* batch_seg = (const int*)d_in[17];

    int* counts    = (int*)d_ws;                  // 40064
    int* offsets   = counts + 40064;              // 40064 (needs 40001)
    int* cursor    = offsets + 40064;             // 40064
    int* blocksums = cursor + 40064;              // 64
    int* csr       = blocksums + 64;              // 200000
    float* W2p     = (float*)(csr + 200000);      // 10240 floats
    unsigned int* Tb = (unsigned int*)(W2p + 10240); // 10000*128 uints = 5.12 MB
    float* peratom = (float*)(Tb + (size_t)NATOMS * 128); // 10000 floats

    zero_counts_kernel<<<SCAN_BLOCKS, 1024, 0, stream>>>(counts);
    prep_count_kernel<<<40 + (NEDGES + 255)/256, 256, 0, stream>>>(
        emb, wm0, wm1, wm2, wm3, W2p, receivers, senders, species, counts);
    scan1_kernel<<<SCAN_BLOCKS, 1024, 0, stream>>>(counts, offsets, blocksums);
    scan3_kernel<<<SCAN_BLOCKS, 1024, 0, stream>>>(offsets, cursor, blocksums);
    scatter_kernel<<<(NEDGES + 255)/256, 256, 0, stream>>>(receivers, senders, species, cursor, csr);
    edge_tbuild_kernel<<<NATOMS/16, 256, 0, stream>>>(
        pos, wr0, wr1, wr2, wr3, senders, receivers, csr, offsets, Tb);
    mix_kernel<<<250, 512, 0, stream>>>(
        Tb, W2p, emb2, wout, cw, scal, species, peratom);
    outsum_kernel<<<1, 1024, 0, stream>>>(
        peratom, batch_seg, (float*)d_out, out_size);
}

// Round 29
// 78.652 us; speedup vs baseline: 1.1333x; 1.1333x over previous
//
#include <hip/hip_runtime.h>
#include <math.h>

#define NATOMS 10000
#define NEDGES 200000
#define NBINS  40000   // (receiver, species) bins = NATOMS*4
#define SCAN_BLOCKS 40 // 40*1024 >= NBINS

// CSR sorted by (receiver, species). Per-edge 60 bf16 values live only in LDS.
// T tile per atom: 256 bf16 (4 species x 64 PADDED slots), stored as 128 uints.
// word k of species s = slots (2k, 2k+1); slot order l0@0, l1@8, l2@28, l3@48;
// pads at 26,27,62,63 (zeroed). even slot -> low 16 bits.
// W2p layout: 80 rows x 64 float2; row = lbase + s*Nl + n, lbase l0@0,l1@32,l2@56,l3@72.
// float2 = (channel j, channel j+64) for lane j.

__device__ __forceinline__ unsigned short f2bf(float f) {
    unsigned int u = __float_as_uint(f);
    u += 0x7FFFu + ((u >> 16) & 1u);   // round-to-nearest-even
    return (unsigned short)(u >> 16);
}

__device__ __forceinline__ float bf2f(unsigned short h) {
    return __uint_as_float(((unsigned int)h) << 16);
}

// unpack slot idx from a 32-word bf16 species row (LDS or global)
__device__ __forceinline__ float tval(const unsigned int* ts, int idx) {
    unsigned int u = ts[idx >> 1];
    return __uint_as_float((idx & 1) ? (u & 0xFFFF0000u) : (u << 16));
}

// Parallel zero of counts (the runtime's fillBuffer uses a tiny grid).
__global__ __launch_bounds__(1024) void zero_counts_kernel(int* __restrict__ counts)
{
    int i = blockIdx.x * 1024 + threadIdx.x;
    if (i < NBINS) counts[i] = 0;
}

// blocks [0,40): prep W2p (10240 elems, float2-pair layout). rest: count edges.
__global__ __launch_bounds__(256) void prep_count_kernel(
    const float* __restrict__ emb,
    const float* __restrict__ wm0, const float* __restrict__ wm1,
    const float* __restrict__ wm2, const float* __restrict__ wm3,
    float* __restrict__ W2p,
    const int* __restrict__ receivers, const int* __restrict__ senders,
    const int* __restrict__ species, int* __restrict__ counts)
{
    if (blockIdx.x < 40) {
        int tid = blockIdx.x * 256 + threadIdx.x;
        if (tid >= 10240) return;
        const float* wm; int idx, Nl, lbase;
        if (tid < 4096)      { wm = wm0; idx = tid;        Nl = 8; lbase = 0;  }
        else if (tid < 7168) { wm = wm1; idx = tid - 4096; Nl = 6; lbase = 32; }
        else if (tid < 9216) { wm = wm2; idx = tid - 7168; Nl = 4; lbase = 56; }
        else                 { wm = wm3; idx = tid - 9216; Nl = 2; lbase = 72; }
        int j  = idx & 127;
        int sn = idx >> 7;
        int n  = sn % Nl;
        float acc = 0.0f;
        #pragma unroll
        for (int c = 0; c < 16; ++c)
            acc = fmaf(wm[(n*16 + c)*128 + j], emb[(sn / Nl)*16 + c], acc);
        int row = lbase + sn;
        W2p[(row*64 + (j & 63))*2 + (j >> 6)] = acc;
    } else {
        int e = (blockIdx.x - 40) * 256 + threadIdx.x;
        if (e < NEDGES) {
            int key = receivers[e] * 4 + species[senders[e]];
            atomicAdd(&counts[key], 1);
        }
    }
}

__global__ __launch_bounds__(1024) void scan1_kernel(
    const int* __restrict__ counts, int* __restrict__ offsets,
    int* __restrict__ blocksums)
{
    __shared__ int sh[1024];
    const int t = threadIdx.x;
    const int idx = blockIdx.x * 1024 + t;
    const int v = (idx < NBINS) ? counts[idx] : 0;
    sh[t] = v;
    __syncthreads();
    for (int off = 1; off < 1024; off <<= 1) {
        int u = (t >= off) ? sh[t - off] : 0;
        __syncthreads();
        sh[t] += u;
        __syncthreads();
    }
    if (idx < NBINS) offsets[idx] = sh[t] - v;   // block-local exclusive
    if (t == 1023) blocksums[blockIdx.x] = sh[1023];
}

// scan2 folded in: each block sums blocksums[0..bid) itself.
__global__ __launch_bounds__(1024) void scan3_kernel(
    int* __restrict__ offsets, int* __restrict__ cursor,
    const int* __restrict__ blocksums)
{
    __shared__ int sbase;
    if (threadIdx.x == 0) {
        int b = 0;
        for (int k = 0; k < (int)blockIdx.x; ++k) b += blocksums[k];
        sbase = b;
    }
    __syncthreads();
    const int idx = blockIdx.x * 1024 + threadIdx.x;
    if (idx < NBINS) {
        int o = offsets[idx] + sbase;
        offsets[idx] = o;
        cursor[idx]  = o;
    }
    if (idx == 0) offsets[NBINS] = NEDGES;
}

__global__ __launch_bounds__(256) void scatter_kernel(
    const int* __restrict__ receivers, const int* __restrict__ senders,
    const int* __restrict__ species, int* __restrict__ cursor,
    int* __restrict__ csr)
{
    int e = blockIdx.x * 256 + threadIdx.x;
    if (e < NEDGES) {
        int key = receivers[e] * 4 + species[senders[e]];
        int p = atomicAdd(&cursor[key], 1);
        csr[p] = e;
    }
}

// FUSED edge-math + T-build. 625 blocks x 256 threads; block owns 16 atoms.
// Output T is packed bf16 (128 uints/atom) via in-LDS staging transpose.
__global__ __launch_bounds__(256) void edge_tbuild_kernel(
    const float* __restrict__ pos,
    const float* __restrict__ wr0, const float* __restrict__ wr1,
    const float* __restrict__ wr2, const float* __restrict__ wr3,
    const int* __restrict__ senders,
    const int* __restrict__ receivers,
    const int* __restrict__ csr,
    const int* __restrict__ off4,
    unsigned int* __restrict__ Tb)
{
    const int tid  = threadIdx.x;
    const int w    = tid >> 6;
    const int lane = tid & 63;
    const int atomBase = blockIdx.x * 16;
    __shared__ unsigned int raw32[256 * 31];   // 31744 B, stride-31 rows

    int bnd[4][5];
    #pragma unroll
    for (int a = 0; a < 4; ++a)
        #pragma unroll
        for (int s = 0; s < 5; ++s)
            bnd[a][s] = off4[(atomBase + w*4 + a)*4 + s];
    const int blockBeg = off4[atomBase*4];
    const int blockEnd = off4[atomBase*4 + 64];

    float acc[4][4];
    #pragma unroll
    for (int a = 0; a < 4; ++a)
        #pragma unroll
        for (int s = 0; s < 4; ++s) acc[a][s] = 0.0f;

    const int dw   = lane >> 1;            // dword 0..29 (lanes 0..59)
    const int half = lane & 1;

    for (int c = blockBeg; c < blockEnd; c += 256) {
        const int i = c + tid;
        if (i < blockEnd) {
            const int e   = csr[i];
            const int snd = senders[e];
            const int rcv = receivers[e];

            float dx = pos[rcv*3]   - pos[snd*3];
            float dy = pos[rcv*3+1] - pos[snd*3+1];
            float dz = pos[rcv*3+2] - pos[snd*3+2];
            float r = sqrtf(dx*dx + dy*dy + dz*dz + 1e-12f);
            float inv_r = 1.0f / r;
            float x = dx * inv_r, y = dy * inv_r, z = dz * inv_r;

            float xr = fminf(r * 0.2f, 1.0f);
            float s1, c1;
            sincosf(3.14159265358979323846f * xr, &s1, &c1);
            float fcut = 0.5f * (c1 + 1.0f);
            float g = fcut / (xr + 0.001f);

            float bess[8];
            {
                float sm1 = 0.0f, s0 = s1;
                float tc = 2.0f * c1;
                #pragma unroll
                for (int n = 0; n < 8; ++n) {
                    bess[n] = s0 * g;
                    float s2 = tc * s0 - sm1;
                    sm1 = s0; s0 = s2;
                }
            }

            float R0[8], R1[6], R2[4], R3[2];
            #pragma unroll
            for (int n = 0; n < 8; ++n) R0[n] = 0.0f;
            #pragma unroll
            for (int n = 0; n < 6; ++n) R1[n] = 0.0f;
            #pragma unroll
            for (int n = 0; n < 4; ++n) R2[n] = 0.0f;
            #pragma unroll
            for (int n = 0; n < 2; ++n) R3[n] = 0.0f;
            #pragma unroll
            for (int k = 0; k < 8; ++k) {
                float b = bess[k];
                #pragma unroll
                for (int n = 0; n < 8; ++n) R0[n] = fmaf(b, wr0[k*8 + n], R0[n]);
                #pragma unroll
                for (int n = 0; n < 6; ++n) R1[n] = fmaf(b, wr1[k*6 + n], R1[n]);
                #pragma unroll
                for (int n = 0; n < 4; ++n) R2[n] = fmaf(b, wr2[k*4 + n], R2[n]);
                #pragma unroll
                for (int n = 0; n < 2; ++n) R3[n] = fmaf(b, wr3[k*2 + n], R3[n]);
            }

            float xy = x*y, yz = y*z, xz = x*z;
            float x2 = x*x, y2 = y*y, z2 = z*z;
            float sh1v[3] = {0.4886025119029199f*y, 0.4886025119029199f*z, 0.4886025119029199f*x};
            float sh2v[5] = {1.0925484305920792f*xy, 1.0925484305920792f*yz,
                             0.31539156525252005f*(3.0f*z2 - 1.0f),
                             1.0925484305920792f*xz, 0.5462742152960396f*(x2 - y2)};
            float sh3v[7] = {0.5900435899266435f*y*(3.0f*x2 - y2),
                             2.890611442640554f*xy*z,
                             0.4570457994644658f*y*(5.0f*z2 - 1.0f),
                             0.3731763325901154f*z*(5.0f*z2 - 3.0f),
                             0.4570457994644658f*x*(5.0f*z2 - 1.0f),
                             1.445305721320277f*z*(x2 - y2),
                             0.5900435899266435f*x*(x2 - 3.0f*y2)};

            unsigned short h[60];
            #pragma unroll
            for (int n = 0; n < 8; ++n)
                h[n] = f2bf(R0[n] * 0.28209479177387814f);
            #pragma unroll
            for (int n = 0; n < 6; ++n)
                #pragma unroll
                for (int m = 0; m < 3; ++m)
                    h[8 + n*3 + m] = f2bf(R1[n] * sh1v[m]);
            #pragma unroll
            for (int n = 0; n < 4; ++n)
                #pragma unroll
                for (int m = 0; m < 5; ++m)
                    h[26 + n*5 + m] = f2bf(R2[n] * sh2v[m]);
            #pragma unroll
            for (int n = 0; n < 2; ++n)
                #pragma unroll
                for (int m = 0; m < 7; ++m)
                    h[46 + n*7 + m] = f2bf(R3[n] * sh3v[m]);

            unsigned int* dst = &raw32[tid * 31];
            #pragma unroll
            for (int k = 0; k < 30; ++k)
                dst[k] = (unsigned int)h[2*k] | ((unsigned int)h[2*k+1] << 16);
        }
        __syncthreads();

        const int n = (blockEnd - c < 256) ? (blockEnd - c) : 256;
        if (lane < 60) {
            #pragma unroll
            for (int a = 0; a < 4; ++a) {
                #pragma unroll
                for (int s = 0; s < 4; ++s) {
                    const int lo = (bnd[a][s]   > c     ? bnd[a][s]   : c)     - c;
                    const int hi = (bnd[a][s+1] < c + n ? bnd[a][s+1] : c + n) - c;
                    float v = acc[a][s];
                    for (int r = lo; r < hi; ++r) {
                        unsigned int u = raw32[r*31 + dw];
                        v += bf2f(half ? (unsigned short)(u >> 16)
                                       : (unsigned short)(u & 0xFFFFu));
                    }
                    acc[a][s] = v;
                }
            }
        }
        __syncthreads();   // before next chunk overwrites raw32
    }

    // ---- pack T to bf16 via LDS staging (reuse raw32 as float stage) ----
    float* stageF = (float*)raw32;   // [w][a][s][64] floats = 16 KB
    const int pl = lane + (lane >= 26 ? 2 : 0);   // packed->padded
    if (lane < 60) {
        #pragma unroll
        for (int a = 0; a < 4; ++a)
            #pragma unroll
            for (int s = 0; s < 4; ++s)
                stageF[(((w*4 + a)*4 + s) << 6) + pl] = acc[a][s];
    } else {
        int p = lane - 60;
        int pi = (p < 2) ? (26 + p) : (62 + (p - 2));
        #pragma unroll
        for (int a = 0; a < 4; ++a)
            #pragma unroll
            for (int s = 0; s < 4; ++s)
                stageF[(((w*4 + a)*4 + s) << 6) + pi] = 0.0f;
    }
    __syncthreads();

    const int wi = lane & 31;        // word index within species row
    const int sh = lane >> 5;        // 0/1
    #pragma unroll
    for (int a = 0; a < 4; ++a) {
        const int atom = atomBase + w*4 + a;
        #pragma unroll
        for (int pass = 0; pass < 2; ++pass) {
            const int s = sh + pass*2;
            const float* src = &stageF[(((w*4 + a)*4 + s) << 6)];
            unsigned int word = (unsigned int)f2bf(src[2*wi])
                              | ((unsigned int)f2bf(src[2*wi + 1]) << 16);
            Tb[(size_t)atom*128 + s*32 + wi] = word;
        }
    }
}

// 250 blocks x 512 threads (8 waves). PURE-DS inner loop (r20 proven);
// epilogue writes peratom[] with a plain store (no contended atomics).
__global__ __launch_bounds__(512) void mix_kernel(
    const unsigned int* __restrict__ Tb,
    const float* __restrict__ W2p,
    const float* __restrict__ emb2,
    const float* __restrict__ w_out,
    const float* __restrict__ comp_weights,
    const float* __restrict__ scaling,
    const int* __restrict__ species,
    float* __restrict__ peratom)
{
    const int tid  = threadIdx.x;
    const int w    = tid >> 6;
    const int lane = tid & 63;
    __shared__ float2 Wl[5120];        // 80 rows x 64 lanes, 40 KB
    __shared__ unsigned int TlS[5120]; // 40 atoms x 128 words, 20 KB

    const float2* Wg = (const float2*)W2p;
    #pragma unroll
    for (int k = 0; k < 10; ++k) Wl[k*512 + tid] = Wg[k*512 + tid];
    const unsigned int* Tsrc = Tb + (size_t)blockIdx.x * 40 * 128;
    #pragma unroll
    for (int k = 0; k < 10; ++k) TlS[k*512 + tid] = Tsrc[k*512 + tid];
    __syncthreads();

    const float scal = scaling[0];
    const int atom0 = blockIdx.x * 40 + w * 5;

    #pragma unroll 1
    for (int i = 0; i < 5; ++i) {
        const int atom = atom0 + i;
        const unsigned int* tb = &TlS[(w*5 + i) * 128];

        float aa0_0 = 0.f, aa0_1 = 0.f;
        float b1_0[3] = {0.f,0.f,0.f},           b1_1[3] = {0.f,0.f,0.f};
        float b2_0[5] = {0.f,0.f,0.f,0.f,0.f},   b2_1[5] = {0.f,0.f,0.f,0.f,0.f};
        float b3_0[7] = {0.f,0.f,0.f,0.f,0.f,0.f,0.f};
        float b3_1[7] = {0.f,0.f,0.f,0.f,0.f,0.f,0.f};

        #pragma unroll
        for (int s = 0; s < 4; ++s) {
            const unsigned int* ts = tb + s * 32;   // LDS, uniform addr -> broadcast
            #pragma unroll
            for (int n = 0; n < 8; ++n) {
                float tv = tval(ts, n);
                float2 wv = Wl[(s*8+n)*64 + lane];
                aa0_0 = fmaf(wv.x, tv, aa0_0);
                aa0_1 = fmaf(wv.y, tv, aa0_1);
            }
            #pragma unroll
            for (int n = 0; n < 6; ++n) {
                float2 wv = Wl[(32 + s*6+n)*64 + lane];
                #pragma unroll
                for (int m = 0; m < 3; ++m) {
                    float tv = tval(ts, 8 + n*3 + m);
                    b1_0[m] = fmaf(wv.x, tv, b1_0[m]);
                    b1_1[m] = fmaf(wv.y, tv, b1_1[m]);
                }
            }
            #pragma unroll
            for (int n = 0; n < 4; ++n) {
                float2 wv = Wl[(56 + s*4+n)*64 + lane];
                #pragma unroll
                for (int m = 0; m < 5; ++m) {
                    float tv = tval(ts, 28 + n*5 + m);
                    b2_0[m] = fmaf(wv.x, tv, b2_0[m]);
                    b2_1[m] = fmaf(wv.y, tv, b2_1[m]);
                }
            }
            #pragma unroll
            for (int n = 0; n < 2; ++n) {
                float2 wv = Wl[(72 + s*2+n)*64 + lane];
                #pragma unroll
                for (int m = 0; m < 7; ++m) {
                    float tv = tval(ts, 48 + n*7 + m);
                    b3_0[m] = fmaf(wv.x, tv, b3_0[m]);
                    b3_1[m] = fmaf(wv.y, tv, b3_1[m]);
                }
            }
        }

        float Bj0 = aa0_0 * aa0_0;
        float Bj1 = aa0_1 * aa0_1;
        Bj0 += (b1_0[0]*b1_0[0] + b1_0[1]*b1_0[1] + b1_0[2]*b1_0[2]) * 0.57735026918962576f;
        Bj1 += (b1_1[0]*b1_1[0] + b1_1[1]*b1_1[1] + b1_1[2]*b1_1[2]) * 0.57735026918962576f;
        {
            float s0 = 0.f, s1v = 0.f;
            #pragma unroll
            for (int m = 0; m < 5; ++m) { s0 = fmaf(b2_0[m], b2_0[m], s0); s1v = fmaf(b2_1[m], b2_1[m], s1v); }
            Bj0 += s0 * 0.44721359549995794f;
            Bj1 += s1v * 0.44721359549995794f;
        }
        {
            float s0 = 0.f, s1v = 0.f;
            #pragma unroll
            for (int m = 0; m < 7; ++m) { s0 = fmaf(b3_0[m], b3_0[m], s0); s1v = fmaf(b3_1[m], b3_1[m], s1v); }
            Bj0 += s0 * 0.37796447300922725f;
            Bj1 += s1v * 0.37796447300922725f;
        }

        const int sp = species[atom];
        float v = Bj0 * Bj0 * emb2[sp*128 + lane] * w_out[lane]
                + Bj1 * Bj1 * emb2[sp*128 + lane + 64] * w_out[lane + 64];

        #pragma unroll
        for (int o = 32; o > 0; o >>= 1) v += __shfl_down(v, o, 64);
        if (lane == 0)
            peratom[atom] = fmaf(v, scal, comp_weights[sp]);   // plain store
    }
}

// Atomic-free segmented reduction: block s sums peratom where batch_seg==s
// (predicated grid-stride; batch_seg sorted but no atomics so no serialization),
// then plain store to out[s]. 128 blocks x 256 threads.
__global__ __launch_bounds__(256) void outsum_kernel(
    const float* __restrict__ peratom,
    const int* __restrict__ batch_seg,
    float* __restrict__ out, int out_size)
{
    const int s = blockIdx.x;
    const int t = threadIdx.x;
    float acc = 0.0f;
    for (int i = t; i < NATOMS; i += 256)
        acc += (batch_seg[i] == s) ? peratom[i] : 0.0f;
    __shared__ float part[4];
    #pragma unroll
    for (int o = 32; o > 0; o >>= 1) acc += __shfl_down(acc, o, 64);
    if ((t & 63) == 0) part[t >> 6] = acc;
    __syncthreads();
    if (t == 0 && s < out_size)
        out[s] = part[0] + part[1] + part[2] + part[3];
}

extern "C" void kernel_launch(void* const* d_in, const int* in_sizes, int n_in,
                              void* d_out, int out_size, void* d_ws, size_t ws_size,
                              hipStream_t stream)
{
    const float* pos  = (const float*)d_in[0];
    const float* emb  = (const float*)d_in[1];
    const float* wr0  = (const float*)d_in[2];
    const float* wm0  = (const float*)d_in[3];
    const float* wr1  = (const float*)d_in[4];
    const float* wm1  = (const float*)d_in[5];
    const float* wr2  = (const float*)d_in[6];
    const float* wm2  = (const float*)d_in[7];
    const float* wr3  = (const float*)d_in[8];
    const float* wm3  = (const float*)d_in[9];
    const float* emb2 = (const float*)d_in[10];
    const float* wout = (const float*)d_in[11];
    const float* cw   = (const float*)d_in[12];
    const float* scal = (const float*)d_in[13];
    const int* species   = (const int*)d_in[14];
    const int* senders   = (const int*)d_in[15];
    const int* receivers = (const int*)d_in[16];
    const int* batch_seg = (const int*)d_in[17];

    int* counts    = (int*)d_ws;                  // 40064
    int* offsets   = counts + 40064;              // 40064 (needs 40001)
    int* cursor    = offsets + 40064;             // 40064
    int* blocksums = cursor + 40064;              // 64
    int* csr       = blocksums + 64;              // 200000
    float* W2p     = (float*)(csr + 200000);      // 10240 floats
    unsigned int* Tb = (unsigned int*)(W2p + 10240); // 10000*128 uints = 5.12 MB
    float* peratom = (float*)(Tb + (size_t)NATOMS * 128); // 10000 floats

    zero_counts_kernel<<<SCAN_BLOCKS, 1024, 0, stream>>>(counts);
    prep_count_kernel<<<40 + (NEDGES + 255)/256, 256, 0, stream>>>(
        emb, wm0, wm1, wm2, wm3, W2p, receivers, senders, species, counts);
    scan1_kernel<<<SCAN_BLOCKS, 1024, 0, stream>>>(counts, offsets, blocksums);
    scan3_kernel<<<SCAN_BLOCKS, 1024, 0, stream>>>(offsets, cursor, blocksums);
    scatter_kernel<<<(NEDGES + 255)/256, 256, 0, stream>>>(receivers, senders, species, cursor, csr);
    edge_tbuild_kernel<<<NATOMS/16, 256, 0, stream>>>(
        pos, wr0, wr1, wr2, wr3, senders, receivers, csr, offsets, Tb);
    mix_kernel<<<250, 512, 0, stream>>>(
        Tb, W2p, emb2, wout, cw, scal, species, peratom);
    outsum_kernel<<<128, 256, 0, stream>>>(
        peratom, batch_seg, (float*)d_out, out_size);
}

// Round 30
// 71.239 us; speedup vs baseline: 1.2512x; 1.1041x over previous
//
#include <hip/hip_runtime.h>
#include <math.h>

#define NATOMS 10000
#define NEDGES 200000
#define NBINS  40000   // (receiver, species) bins = NATOMS*4
#define SCAN_BLOCKS 40 // 40*1024 >= NBINS

// CSR sorted by (receiver, species). Per-edge 60 bf16 values live only in LDS.
// T tile per atom: 256 bf16 (4 species x 64 PADDED slots), stored as 128 uints.
// word k of species s = slots (2k, 2k+1); slot order l0@0, l1@8, l2@28, l3@48;
// pads at 26,27,62,63 (zeroed). even slot -> low 16 bits.
// W2p layout: 80 rows x 64 float2; row = lbase + s*Nl + n, lbase l0@0,l1@32,l2@56,l3@72.
// float2 = (channel j, channel j+64) for lane j.

__device__ __forceinline__ unsigned short f2bf(float f) {
    unsigned int u = __float_as_uint(f);
    u += 0x7FFFu + ((u >> 16) & 1u);   // round-to-nearest-even
    return (unsigned short)(u >> 16);
}

__device__ __forceinline__ float bf2f(unsigned short h) {
    return __uint_as_float(((unsigned int)h) << 16);
}

// unpack slot idx from a 32-word bf16 species row (LDS or global)
__device__ __forceinline__ float tval(const unsigned int* ts, int idx) {
    unsigned int u = ts[idx >> 1];
    return __uint_as_float((idx & 1) ? (u & 0xFFFF0000u) : (u << 16));
}

// Parallel zero of counts AND d_out (runtime fillBuffer is pathologically slow).
__global__ __launch_bounds__(1024) void zero_kernel(
    int* __restrict__ counts, float* __restrict__ out, int out_size)
{
    int i = blockIdx.x * 1024 + threadIdx.x;
    if (i < NBINS) counts[i] = 0;
    if (blockIdx.x == 0 && threadIdx.x < out_size) out[threadIdx.x] = 0.0f;
}

// blocks [0,40): prep W2p (10240 elems, float2-pair layout). rest: count edges.
__global__ __launch_bounds__(256) void prep_count_kernel(
    const float* __restrict__ emb,
    const float* __restrict__ wm0, const float* __restrict__ wm1,
    const float* __restrict__ wm2, const float* __restrict__ wm3,
    float* __restrict__ W2p,
    const int* __restrict__ receivers, const int* __restrict__ senders,
    const int* __restrict__ species, int* __restrict__ counts)
{
    if (blockIdx.x < 40) {
        int tid = blockIdx.x * 256 + threadIdx.x;
        if (tid >= 10240) return;
        const float* wm; int idx, Nl, lbase;
        if (tid < 4096)      { wm = wm0; idx = tid;        Nl = 8; lbase = 0;  }
        else if (tid < 7168) { wm = wm1; idx = tid - 4096; Nl = 6; lbase = 32; }
        else if (tid < 9216) { wm = wm2; idx = tid - 7168; Nl = 4; lbase = 56; }
        else                 { wm = wm3; idx = tid - 9216; Nl = 2; lbase = 72; }
        int j  = idx & 127;
        int sn = idx >> 7;
        int n  = sn % Nl;
        float acc = 0.0f;
        #pragma unroll
        for (int c = 0; c < 16; ++c)
            acc = fmaf(wm[(n*16 + c)*128 + j], emb[(sn / Nl)*16 + c], acc);
        int row = lbase + sn;
        W2p[(row*64 + (j & 63))*2 + (j >> 6)] = acc;
    } else {
        int e = (blockIdx.x - 40) * 256 + threadIdx.x;
        if (e < NEDGES) {
            int key = receivers[e] * 4 + species[senders[e]];
            atomicAdd(&counts[key], 1);
        }
    }
}

__global__ __launch_bounds__(1024) void scan1_kernel(
    const int* __restrict__ counts, int* __restrict__ offsets,
    int* __restrict__ blocksums)
{
    __shared__ int sh[1024];
    const int t = threadIdx.x;
    const int idx = blockIdx.x * 1024 + t;
    const int v = (idx < NBINS) ? counts[idx] : 0;
    sh[t] = v;
    __syncthreads();
    for (int off = 1; off < 1024; off <<= 1) {
        int u = (t >= off) ? sh[t - off] : 0;
        __syncthreads();
        sh[t] += u;
        __syncthreads();
    }
    if (idx < NBINS) offsets[idx] = sh[t] - v;   // block-local exclusive
    if (t == 1023) blocksums[blockIdx.x] = sh[1023];
}

// scan2 folded in: each block sums blocksums[0..bid) itself.
__global__ __launch_bounds__(1024) void scan3_kernel(
    int* __restrict__ offsets, int* __restrict__ cursor,
    const int* __restrict__ blocksums)
{
    __shared__ int sbase;
    if (threadIdx.x == 0) {
        int b = 0;
        for (int k = 0; k < (int)blockIdx.x; ++k) b += blocksums[k];
        sbase = b;
    }
    __syncthreads();
    const int idx = blockIdx.x * 1024 + threadIdx.x;
    if (idx < NBINS) {
        int o = offsets[idx] + sbase;
        offsets[idx] = o;
        cursor[idx]  = o;
    }
    if (idx == 0) offsets[NBINS] = NEDGES;
}

__global__ __launch_bounds__(256) void scatter_kernel(
    const int* __restrict__ receivers, const int* __restrict__ senders,
    const int* __restrict__ species, int* __restrict__ cursor,
    int* __restrict__ csr)
{
    int e = blockIdx.x * 256 + threadIdx.x;
    if (e < NEDGES) {
        int key = receivers[e] * 4 + species[senders[e]];
        int p = atomicAdd(&cursor[key], 1);
        csr[p] = e;
    }
}

// FUSED edge-math + T-build. 625 blocks x 256 threads; block owns 16 atoms.
// Output T is packed bf16 (128 uints/atom) via in-LDS staging transpose.
__global__ __launch_bounds__(256) void edge_tbuild_kernel(
    const float* __restrict__ pos,
    const float* __restrict__ wr0, const float* __restrict__ wr1,
    const float* __restrict__ wr2, const float* __restrict__ wr3,
    const int* __restrict__ senders,
    const int* __restrict__ receivers,
    const int* __restrict__ csr,
    const int* __restrict__ off4,
    unsigned int* __restrict__ Tb)
{
    const int tid  = threadIdx.x;
    const int w    = tid >> 6;
    const int lane = tid & 63;
    const int atomBase = blockIdx.x * 16;
    __shared__ unsigned int raw32[256 * 31];   // 31744 B, stride-31 rows

    int bnd[4][5];
    #pragma unroll
    for (int a = 0; a < 4; ++a)
        #pragma unroll
        for (int s = 0; s < 5; ++s)
            bnd[a][s] = off4[(atomBase + w*4 + a)*4 + s];
    const int blockBeg = off4[atomBase*4];
    const int blockEnd = off4[atomBase*4 + 64];

    float acc[4][4];
    #pragma unroll
    for (int a = 0; a < 4; ++a)
        #pragma unroll
        for (int s = 0; s < 4; ++s) acc[a][s] = 0.0f;

    const int dw   = lane >> 1;            // dword 0..29 (lanes 0..59)
    const int half = lane & 1;

    for (int c = blockBeg; c < blockEnd; c += 256) {
        const int i = c + tid;
        if (i < blockEnd) {
            const int e   = csr[i];
            const int snd = senders[e];
            const int rcv = receivers[e];

            float dx = pos[rcv*3]   - pos[snd*3];
            float dy = pos[rcv*3+1] - pos[snd*3+1];
            float dz = pos[rcv*3+2] - pos[snd*3+2];
            float r = sqrtf(dx*dx + dy*dy + dz*dz + 1e-12f);
            float inv_r = 1.0f / r;
            float x = dx * inv_r, y = dy * inv_r, z = dz * inv_r;

            float xr = fminf(r * 0.2f, 1.0f);
            float s1, c1;
            sincosf(3.14159265358979323846f * xr, &s1, &c1);
            float fcut = 0.5f * (c1 + 1.0f);
            float g = fcut / (xr + 0.001f);

            float bess[8];
            {
                float sm1 = 0.0f, s0 = s1;
                float tc = 2.0f * c1;
                #pragma unroll
                for (int n = 0; n < 8; ++n) {
                    bess[n] = s0 * g;
                    float s2 = tc * s0 - sm1;
                    sm1 = s0; s0 = s2;
                }
            }

            float R0[8], R1[6], R2[4], R3[2];
            #pragma unroll
            for (int n = 0; n < 8; ++n) R0[n] = 0.0f;
            #pragma unroll
            for (int n = 0; n < 6; ++n) R1[n] = 0.0f;
            #pragma unroll
            for (int n = 0; n < 4; ++n) R2[n] = 0.0f;
            #pragma unroll
            for (int n = 0; n < 2; ++n) R3[n] = 0.0f;
            #pragma unroll
            for (int k = 0; k < 8; ++k) {
                float b = bess[k];
                #pragma unroll
                for (int n = 0; n < 8; ++n) R0[n] = fmaf(b, wr0[k*8 + n], R0[n]);
                #pragma unroll
                for (int n = 0; n < 6; ++n) R1[n] = fmaf(b, wr1[k*6 + n], R1[n]);
                #pragma unroll
                for (int n = 0; n < 4; ++n) R2[n] = fmaf(b, wr2[k*4 + n], R2[n]);
                #pragma unroll
                for (int n = 0; n < 2; ++n) R3[n] = fmaf(b, wr3[k*2 + n], R3[n]);
            }

            float xy = x*y, yz = y*z, xz = x*z;
            float x2 = x*x, y2 = y*y, z2 = z*z;
            float sh1v[3] = {0.4886025119029199f*y, 0.4886025119029199f*z, 0.4886025119029199f*x};
            float sh2v[5] = {1.0925484305920792f*xy, 1.0925484305920792f*yz,
                             0.31539156525252005f*(3.0f*z2 - 1.0f),
                             1.0925484305920792f*xz, 0.5462742152960396f*(x2 - y2)};
            float sh3v[7] = {0.5900435899266435f*y*(3.0f*x2 - y2),
                             2.890611442640554f*xy*z,
                             0.4570457994644658f*y*(5.0f*z2 - 1.0f),
                             0.3731763325901154f*z*(5.0f*z2 - 3.0f),
                             0.4570457994644658f*x*(5.0f*z2 - 1.0f),
                             1.445305721320277f*z*(x2 - y2),
                             0.5900435899266435f*x*(x2 - 3.0f*y2)};

            unsigned short h[60];
            #pragma unroll
            for (int n = 0; n < 8; ++n)
                h[n] = f2bf(R0[n] * 0.28209479177387814f);
            #pragma unroll
            for (int n = 0; n < 6; ++n)
                #pragma unroll
                for (int m = 0; m < 3; ++m)
                    h[8 + n*3 + m] = f2bf(R1[n] * sh1v[m]);
            #pragma unroll
            for (int n = 0; n < 4; ++n)
                #pragma unroll
                for (int m = 0; m < 5; ++m)
                    h[26 + n*5 + m] = f2bf(R2[n] * sh2v[m]);
            #pragma unroll
            for (int n = 0; n < 2; ++n)
                #pragma unroll
                for (int m = 0; m < 7; ++m)
                    h[46 + n*7 + m] = f2bf(R3[n] * sh3v[m]);

            unsigned int* dst = &raw32[tid * 31];
            #pragma unroll
            for (int k = 0; k < 30; ++k)
                dst[k] = (unsigned int)h[2*k] | ((unsigned int)h[2*k+1] << 16);
        }
        __syncthreads();

        const int n = (blockEnd - c < 256) ? (blockEnd - c) : 256;
        if (lane < 60) {
            #pragma unroll
            for (int a = 0; a < 4; ++a) {
                #pragma unroll
                for (int s = 0; s < 4; ++s) {
                    const int lo = (bnd[a][s]   > c     ? bnd[a][s]   : c)     - c;
                    const int hi = (bnd[a][s+1] < c + n ? bnd[a][s+1] : c + n) - c;
                    float v = acc[a][s];
                    for (int r = lo; r < hi; ++r) {
                        unsigned int u = raw32[r*31 + dw];
                        v += bf2f(half ? (unsigned short)(u >> 16)
                                       : (unsigned short)(u & 0xFFFFu));
                    }
                    acc[a][s] = v;
                }
            }
        }
        __syncthreads();   // before next chunk overwrites raw32
    }

    // ---- pack T to bf16 via LDS staging (reuse raw32 as float stage) ----
    float* stageF = (float*)raw32;   // [w][a][s][64] floats = 16 KB
    const int pl = lane + (lane >= 26 ? 2 : 0);   // packed->padded
    if (lane < 60) {
        #pragma unroll
        for (int a = 0; a < 4; ++a)
            #pragma unroll
            for (int s = 0; s < 4; ++s)
                stageF[(((w*4 + a)*4 + s) << 6) + pl] = acc[a][s];
    } else {
        int p = lane - 60;
        int pi = (p < 2) ? (26 + p) : (62 + (p - 2));
        #pragma unroll
        for (int a = 0; a < 4; ++a)
            #pragma unroll
            for (int s = 0; s < 4; ++s)
                stageF[(((w*4 + a)*4 + s) << 6) + pi] = 0.0f;
    }
    __syncthreads();

    const int wi = lane & 31;        // word index within species row
    const int sh = lane >> 5;        // 0/1
    #pragma unroll
    for (int a = 0; a < 4; ++a) {
        const int atom = atomBase + w*4 + a;
        #pragma unroll
        for (int pass = 0; pass < 2; ++pass) {
            const int s = sh + pass*2;
            const float* src = &stageF[(((w*4 + a)*4 + s) << 6)];
            unsigned int word = (unsigned int)f2bf(src[2*wi])
                              | ((unsigned int)f2bf(src[2*wi + 1]) << 16);
            Tb[(size_t)atom*128 + s*32 + wi] = word;
        }
    }
}

// 250 blocks x 512 threads (8 waves). PURE-DS inner loop (r20 proven);
// epilogue accumulates per-structure partials in LDS (block's 40 consecutive
// atoms span <=3 structures), then ~3 global atomics per block into zeroed out.
__global__ __launch_bounds__(512) void mix_kernel(
    const unsigned int* __restrict__ Tb,
    const float* __restrict__ W2p,
    const float* __restrict__ emb2,
    const float* __restrict__ w_out,
    const float* __restrict__ comp_weights,
    const float* __restrict__ scaling,
    const int* __restrict__ species,
    const int* __restrict__ batch_seg,
    float* __restrict__ out)
{
    const int tid  = threadIdx.x;
    const int w    = tid >> 6;
    const int lane = tid & 63;
    __shared__ float2 Wl[5120];        // 80 rows x 64 lanes, 40 KB
    __shared__ unsigned int TlS[5120]; // 40 atoms x 128 words, 20 KB
    __shared__ float sacc[128];

    if (tid < 128) sacc[tid] = 0.0f;
    const float2* Wg = (const float2*)W2p;
    #pragma unroll
    for (int k = 0; k < 10; ++k) Wl[k*512 + tid] = Wg[k*512 + tid];
    const unsigned int* Tsrc = Tb + (size_t)blockIdx.x * 40 * 128;
    #pragma unroll
    for (int k = 0; k < 10; ++k) TlS[k*512 + tid] = Tsrc[k*512 + tid];
    __syncthreads();

    const float scal = scaling[0];
    const int atom0 = blockIdx.x * 40 + w * 5;

    #pragma unroll 1
    for (int i = 0; i < 5; ++i) {
        const int atom = atom0 + i;
        const unsigned int* tb = &TlS[(w*5 + i) * 128];

        float aa0_0 = 0.f, aa0_1 = 0.f;
        float b1_0[3] = {0.f,0.f,0.f},           b1_1[3] = {0.f,0.f,0.f};
        float b2_0[5] = {0.f,0.f,0.f,0.f,0.f},   b2_1[5] = {0.f,0.f,0.f,0.f,0.f};
        float b3_0[7] = {0.f,0.f,0.f,0.f,0.f,0.f,0.f};
        float b3_1[7] = {0.f,0.f,0.f,0.f,0.f,0.f,0.f};

        #pragma unroll
        for (int s = 0; s < 4; ++s) {
            const unsigned int* ts = tb + s * 32;   // LDS, uniform addr -> broadcast
            #pragma unroll
            for (int n = 0; n < 8; ++n) {
                float tv = tval(ts, n);
                float2 wv = Wl[(s*8+n)*64 + lane];
                aa0_0 = fmaf(wv.x, tv, aa0_0);
                aa0_1 = fmaf(wv.y, tv, aa0_1);
            }
            #pragma unroll
            for (int n = 0; n < 6; ++n) {
                float2 wv = Wl[(32 + s*6+n)*64 + lane];
                #pragma unroll
                for (int m = 0; m < 3; ++m) {
                    float tv = tval(ts, 8 + n*3 + m);
                    b1_0[m] = fmaf(wv.x, tv, b1_0[m]);
                    b1_1[m] = fmaf(wv.y, tv, b1_1[m]);
                }
            }
            #pragma unroll
            for (int n = 0; n < 4; ++n) {
                float2 wv = Wl[(56 + s*4+n)*64 + lane];
                #pragma unroll
                for (int m = 0; m < 5; ++m) {
                    float tv = tval(ts, 28 + n*5 + m);
                    b2_0[m] = fmaf(wv.x, tv, b2_0[m]);
                    b2_1[m] = fmaf(wv.y, tv, b2_1[m]);
                }
            }
            #pragma unroll
            for (int n = 0; n < 2; ++n) {
                float2 wv = Wl[(72 + s*2+n)*64 + lane];
                #pragma unroll
                for (int m = 0; m < 7; ++m) {
                    float tv = tval(ts, 48 + n*7 + m);
                    b3_0[m] = fmaf(wv.x, tv, b3_0[m]);
                    b3_1[m] = fmaf(wv.y, tv, b3_1[m]);
                }
            }
        }

        float Bj0 = aa0_0 * aa0_0;
        float Bj1 = aa0_1 * aa0_1;
        Bj0 += (b1_0[0]*b1_0[0] + b1_0[1]*b1_0[1] + b1_0[2]*b1_0[2]) * 0.57735026918962576f;
        Bj1 += (b1_1[0]*b1_1[0] + b1_1[1]*b1_1[1] + b1_1[2]*b1_1[2]) * 0.57735026918962576f;
        {
            float s0 = 0.f, s1v = 0.f;
            #pragma unroll
            for (int m = 0; m < 5; ++m) { s0 = fmaf(b2_0[m], b2_0[m], s0); s1v = fmaf(b2_1[m], b2_1[m], s1v); }
            Bj0 += s0 * 0.44721359549995794f;
            Bj1 += s1v * 0.44721359549995794f;
        }
        {
            float s0 = 0.f, s1v = 0.f;
            #pragma unroll
            for (int m = 0; m < 7; ++m) { s0 = fmaf(b3_0[m], b3_0[m], s0); s1v = fmaf(b3_1[m], b3_1[m], s1v); }
            Bj0 += s0 * 0.37796447300922725f;
            Bj1 += s1v * 0.37796447300922725f;
        }

        const int sp = species[atom];
        float v = Bj0 * Bj0 * emb2[sp*128 + lane] * w_out[lane]
                + Bj1 * Bj1 * emb2[sp*128 + lane + 64] * w_out[lane + 64];

        #pragma unroll
        for (int o = 32; o > 0; o >>= 1) v += __shfl_down(v, o, 64);
        if (lane == 0)
            atomicAdd(&sacc[batch_seg[atom]], fmaf(v, scal, comp_weights[sp]));
    }

    __syncthreads();
    if (tid < 128) {
        float p = sacc[tid];
        if (p != 0.0f) atomicAdd(&out[tid], p);
    }
}

extern "C" void kernel_launch(void* const* d_in, const int* in_sizes, int n_in,
                              void* d_out, int out_size, void* d_ws, size_t ws_size,
                              hipStream_t stream)
{
    const float* pos  = (const float*)d_in[0];
    const float* emb  = (const float*)d_in[1];
    const float* wr0  = (const float*)d_in[2];
    const float* wm0  = (const float*)d_in[3];
    const float* wr1  = (const float*)d_in[4];
    const float* wm1  = (const float*)d_in[5];
    const float* wr2  = (const float*)d_in[6];
    const float* wm2  = (const float*)d_in[7];
    const float* wr3  = (const float*)d_in[8];
    const float* wm3  = (const float*)d_in[9];
    const float* emb2 = (const float*)d_in[10];
    const float* wout = (const float*)d_in[11];
    const float* cw   = (const float*)d_in[12];
    const float* scal = (const float*)d_in[13];
    const int* species   = (const int*)d_in[14];
    const int* senders   = (const int*)d_in[15];
    const int* receivers = (const int*)d_in[16];
    const int* batch_seg = (const int*)d_in[17];

    int* counts    = (int*)d_ws;                  // 40064
    int* offsets   = counts + 40064;              // 40064 (needs 40001)
    int* cursor    = offsets + 40064;             // 40064
    int* blocksums = cursor + 40064;              // 64
    int* csr       = blocksums + 64;              // 200000
    float* W2p     = (float*)(csr + 200000);      // 10240 floats
    unsigned int* Tb = (unsigned int*)(W2p + 10240); // 10000*128 uints = 5.12 MB

    zero_kernel<<<SCAN_BLOCKS, 1024, 0, stream>>>(counts, (float*)d_out, out_size);
    prep_count_kernel<<<40 + (NEDGES + 255)/256, 256, 0, stream>>>(
        emb, wm0, wm1, wm2, wm3, W2p, receivers, senders, species, counts);
    scan1_kernel<<<SCAN_BLOCKS, 1024, 0, stream>>>(counts, offsets, blocksums);
    scan3_kernel<<<SCAN_BLOCKS, 1024, 0, stream>>>(offsets, cursor, blocksums);
    scatter_kernel<<<(NEDGES + 255)/256, 256, 0, stream>>>(receivers, senders, species, cursor, csr);
    edge_tbuild_kernel<<<NATOMS/16, 256, 0, stream>>>(
        pos, wr0, wr1, wr2, wr3, senders, receivers, csr, offsets, Tb);
    mix_kernel<<<250, 512, 0, stream>>>(
        Tb, W2p, emb2, wout, cw, scal, species, batch_seg, (float*)d_out);
}

// Round 31
// 64.298 us; speedup vs baseline: 1.3863x; 1.1079x over previous
//
#include <hip/hip_runtime.h>
#include <math.h>

#define NATOMS 10000
#define NEDGES 200000
#define NBINS  40000   // (receiver, species) bins = NATOMS*4
#define SCAN_BLOCKS 40 // 40*1024 >= NBINS

// CSR sorted by (receiver, species). Per-edge 60 bf16 values live only in LDS.
// T tile per atom: 256 bf16 (4 species x 64 PADDED slots), stored as 128 uints.
// word k of species s = slots (2k, 2k+1); slot order l0@0, l1@8, l2@28, l3@48;
// pads at 26,27,62,63 (zeroed). even slot -> low 16 bits.
// W2p layout: 80 rows x 64 float2; row = lbase + s*Nl + n, lbase l0@0,l1@32,l2@56,l3@72.
// float2 = (channel j, channel j+64) for lane j.

__device__ __forceinline__ unsigned short f2bf(float f) {
    unsigned int u = __float_as_uint(f);
    u += 0x7FFFu + ((u >> 16) & 1u);   // round-to-nearest-even
    return (unsigned short)(u >> 16);
}

__device__ __forceinline__ float bf2f(unsigned short h) {
    return __uint_as_float(((unsigned int)h) << 16);
}

// unpack slot idx from a 32-word bf16 species row (LDS or global)
__device__ __forceinline__ float tval(const unsigned int* ts, int idx) {
    unsigned int u = ts[idx >> 1];
    return __uint_as_float((idx & 1) ? (u & 0xFFFF0000u) : (u << 16));
}

// Parallel zero of counts AND d_out (runtime fillBuffer is pathologically slow).
__global__ __launch_bounds__(1024) void zero_kernel(
    int* __restrict__ counts, float* __restrict__ out, int out_size)
{
    int i = blockIdx.x * 1024 + threadIdx.x;
    if (i < NBINS) counts[i] = 0;
    if (blockIdx.x == 0 && threadIdx.x < out_size) out[threadIdx.x] = 0.0f;
}

// blocks [0,40): prep W2p. rest: count edges AND record each edge's rank
// within its bin (the counting atomic's return value) -> atomic-free scatter.
__global__ __launch_bounds__(256) void prep_count_kernel(
    const float* __restrict__ emb,
    const float* __restrict__ wm0, const float* __restrict__ wm1,
    const float* __restrict__ wm2, const float* __restrict__ wm3,
    float* __restrict__ W2p,
    const int* __restrict__ receivers, const int* __restrict__ senders,
    const int* __restrict__ species, int* __restrict__ counts,
    int* __restrict__ rank)
{
    if (blockIdx.x < 40) {
        int tid = blockIdx.x * 256 + threadIdx.x;
        if (tid >= 10240) return;
        const float* wm; int idx, Nl, lbase;
        if (tid < 4096)      { wm = wm0; idx = tid;        Nl = 8; lbase = 0;  }
        else if (tid < 7168) { wm = wm1; idx = tid - 4096; Nl = 6; lbase = 32; }
        else if (tid < 9216) { wm = wm2; idx = tid - 7168; Nl = 4; lbase = 56; }
        else                 { wm = wm3; idx = tid - 9216; Nl = 2; lbase = 72; }
        int j  = idx & 127;
        int sn = idx >> 7;
        int n  = sn % Nl;
        float acc = 0.0f;
        #pragma unroll
        for (int c = 0; c < 16; ++c)
            acc = fmaf(wm[(n*16 + c)*128 + j], emb[(sn / Nl)*16 + c], acc);
        int row = lbase + sn;
        W2p[(row*64 + (j & 63))*2 + (j >> 6)] = acc;
    } else {
        int e = (blockIdx.x - 40) * 256 + threadIdx.x;
        if (e < NEDGES) {
            int key = receivers[e] * 4 + species[senders[e]];
            rank[e] = atomicAdd(&counts[key], 1);
        }
    }
}

__global__ __launch_bounds__(1024) void scan1_kernel(
    const int* __restrict__ counts, int* __restrict__ offsets,
    int* __restrict__ blocksums)
{
    __shared__ int sh[1024];
    const int t = threadIdx.x;
    const int idx = blockIdx.x * 1024 + t;
    const int v = (idx < NBINS) ? counts[idx] : 0;
    sh[t] = v;
    __syncthreads();
    for (int off = 1; off < 1024; off <<= 1) {
        int u = (t >= off) ? sh[t - off] : 0;
        __syncthreads();
        sh[t] += u;
        __syncthreads();
    }
    if (idx < NBINS) offsets[idx] = sh[t] - v;   // block-local exclusive
    if (t == 1023) blocksums[blockIdx.x] = sh[1023];
}

// scan2 folded in: each block sums blocksums[0..bid) itself.
__global__ __launch_bounds__(1024) void scan3_kernel(
    int* __restrict__ offsets, const int* __restrict__ blocksums)
{
    __shared__ int sbase;
    if (threadIdx.x == 0) {
        int b = 0;
        for (int k = 0; k < (int)blockIdx.x; ++k) b += blocksums[k];
        sbase = b;
    }
    __syncthreads();
    const int idx = blockIdx.x * 1024 + threadIdx.x;
    if (idx < NBINS) offsets[idx] += sbase;
    if (idx == 0) offsets[NBINS] = NEDGES;
}

// Atomic-free scatter: destination = offsets[key] + rank[e].
__global__ __launch_bounds__(256) void scatter_kernel(
    const int* __restrict__ receivers, const int* __restrict__ senders,
    const int* __restrict__ species, const int* __restrict__ offsets,
    const int* __restrict__ rank, int* __restrict__ csr)
{
    int e = blockIdx.x * 256 + threadIdx.x;
    if (e < NEDGES) {
        int key = receivers[e] * 4 + species[senders[e]];
        csr[offsets[key] + rank[e]] = e;
    }
}

// FUSED edge-math + T-build. 625 blocks x 256 threads; block owns 16 atoms.
// Output T is packed bf16 (128 uints/atom) via in-LDS staging transpose.
__global__ __launch_bounds__(256) void edge_tbuild_kernel(
    const float* __restrict__ pos,
    const float* __restrict__ wr0, const float* __restrict__ wr1,
    const float* __restrict__ wr2, const float* __restrict__ wr3,
    const int* __restrict__ senders,
    const int* __restrict__ receivers,
    const int* __restrict__ csr,
    const int* __restrict__ off4,
    unsigned int* __restrict__ Tb)
{
    const int tid  = threadIdx.x;
    const int w    = tid >> 6;
    const int lane = tid & 63;
    const int atomBase = blockIdx.x * 16;
    __shared__ unsigned int raw32[256 * 31];   // 31744 B, stride-31 rows

    int bnd[4][5];
    #pragma unroll
    for (int a = 0; a < 4; ++a)
        #pragma unroll
        for (int s = 0; s < 5; ++s)
            bnd[a][s] = off4[(atomBase + w*4 + a)*4 + s];
    const int blockBeg = off4[atomBase*4];
    const int blockEnd = off4[atomBase*4 + 64];

    float acc[4][4];
    #pragma unroll
    for (int a = 0; a < 4; ++a)
        #pragma unroll
        for (int s = 0; s < 4; ++s) acc[a][s] = 0.0f;

    const int dw   = lane >> 1;            // dword 0..29 (lanes 0..59)
    const int half = lane & 1;

    for (int c = blockBeg; c < blockEnd; c += 256) {
        const int i = c + tid;
        if (i < blockEnd) {
            const int e   = csr[i];
            const int snd = senders[e];
            const int rcv = receivers[e];

            float dx = pos[rcv*3]   - pos[snd*3];
            float dy = pos[rcv*3+1] - pos[snd*3+1];
            float dz = pos[rcv*3+2] - pos[snd*3+2];
            float r = sqrtf(dx*dx + dy*dy + dz*dz + 1e-12f);
            float inv_r = 1.0f / r;
            float x = dx * inv_r, y = dy * inv_r, z = dz * inv_r;

            float xr = fminf(r * 0.2f, 1.0f);
            float s1, c1;
            sincosf(3.14159265358979323846f * xr, &s1, &c1);
            float fcut = 0.5f * (c1 + 1.0f);
            float g = fcut / (xr + 0.001f);

            float bess[8];
            {
                float sm1 = 0.0f, s0 = s1;
                float tc = 2.0f * c1;
                #pragma unroll
                for (int n = 0; n < 8; ++n) {
                    bess[n] = s0 * g;
                    float s2 = tc * s0 - sm1;
                    sm1 = s0; s0 = s2;
                }
            }

            float R0[8], R1[6], R2[4], R3[2];
            #pragma unroll
            for (int n = 0; n < 8; ++n) R0[n] = 0.0f;
            #pragma unroll
            for (int n = 0; n < 6; ++n) R1[n] = 0.0f;
            #pragma unroll
            for (int n = 0; n < 4; ++n) R2[n] = 0.0f;
            #pragma unroll
            for (int n = 0; n < 2; ++n) R3[n] = 0.0f;
            #pragma unroll
            for (int k = 0; k < 8; ++k) {
                float b = bess[k];
                #pragma unroll
                for (int n = 0; n < 8; ++n) R0[n] = fmaf(b, wr0[k*8 + n], R0[n]);
                #pragma unroll
                for (int n = 0; n < 6; ++n) R1[n] = fmaf(b, wr1[k*6 + n], R1[n]);
                #pragma unroll
                for (int n = 0; n < 4; ++n) R2[n] = fmaf(b, wr2[k*4 + n], R2[n]);
                #pragma unroll
                for (int n = 0; n < 2; ++n) R3[n] = fmaf(b, wr3[k*2 + n], R3[n]);
            }

            float xy = x*y, yz = y*z, xz = x*z;
            float x2 = x*x, y2 = y*y, z2 = z*z;
            float sh1v[3] = {0.4886025119029199f*y, 0.4886025119029199f*z, 0.4886025119029199f*x};
            float sh2v[5] = {1.0925484305920792f*xy, 1.0925484305920792f*yz,
                             0.31539156525252005f*(3.0f*z2 - 1.0f),
                             1.0925484305920792f*xz, 0.5462742152960396f*(x2 - y2)};
            float sh3v[7] = {0.5900435899266435f*y*(3.0f*x2 - y2),
                             2.890611442640554f*xy*z,
                             0.4570457994644658f*y*(5.0f*z2 - 1.0f),
                             0.3731763325901154f*z*(5.0f*z2 - 3.0f),
                             0.4570457994644658f*x*(5.0f*z2 - 1.0f),
                             1.445305721320277f*z*(x2 - y2),
                             0.5900435899266435f*x*(x2 - 3.0f*y2)};

            unsigned short h[60];
            #pragma unroll
            for (int n = 0; n < 8; ++n)
                h[n] = f2bf(R0[n] * 0.28209479177387814f);
            #pragma unroll
            for (int n = 0; n < 6; ++n)
                #pragma unroll
                for (int m = 0; m < 3; ++m)
                    h[8 + n*3 + m] = f2bf(R1[n] * sh1v[m]);
            #pragma unroll
            for (int n = 0; n < 4; ++n)
                #pragma unroll
                for (int m = 0; m < 5; ++m)
                    h[26 + n*5 + m] = f2bf(R2[n] * sh2v[m]);
            #pragma unroll
            for (int n = 0; n < 2; ++n)
                #pragma unroll
                for (int m = 0; m < 7; ++m)
                    h[46 + n*7 + m] = f2bf(R3[n] * sh3v[m]);

            unsigned int* dst = &raw32[tid * 31];
            #pragma unroll
            for (int k = 0; k < 30; ++k)
                dst[k] = (unsigned int)h[2*k] | ((unsigned int)h[2*k+1] << 16);
        }
        __syncthreads();

        const int n = (blockEnd - c < 256) ? (blockEnd - c) : 256;
        if (lane < 60) {
            #pragma unroll
            for (int a = 0; a < 4; ++a) {
                #pragma unroll
                for (int s = 0; s < 4; ++s) {
                    const int lo = (bnd[a][s]   > c     ? bnd[a][s]   : c)     - c;
                    const int hi = (bnd[a][s+1] < c + n ? bnd[a][s+1] : c + n) - c;
                    float v = acc[a][s];
                    for (int r = lo; r < hi; ++r) {
                        unsigned int u = raw32[r*31 + dw];
                        v += bf2f(half ? (unsigned short)(u >> 16)
                                       : (unsigned short)(u & 0xFFFFu));
                    }
                    acc[a][s] = v;
                }
            }
        }
        __syncthreads();   // before next chunk overwrites raw32
    }

    // ---- pack T to bf16 via LDS staging (reuse raw32 as float stage) ----
    float* stageF = (float*)raw32;   // [w][a][s][64] floats = 16 KB
    const int pl = lane + (lane >= 26 ? 2 : 0);   // packed->padded
    if (lane < 60) {
        #pragma unroll
        for (int a = 0; a < 4; ++a)
            #pragma unroll
            for (int s = 0; s < 4; ++s)
                stageF[(((w*4 + a)*4 + s) << 6) + pl] = acc[a][s];
    } else {
        int p = lane - 60;
        int pi = (p < 2) ? (26 + p) : (62 + (p - 2));
        #pragma unroll
        for (int a = 0; a < 4; ++a)
            #pragma unroll
            for (int s = 0; s < 4; ++s)
                stageF[(((w*4 + a)*4 + s) << 6) + pi] = 0.0f;
    }
    __syncthreads();

    const int wi = lane & 31;        // word index within species row
    const int sh = lane >> 5;        // 0/1
    #pragma unroll
    for (int a = 0; a < 4; ++a) {
        const int atom = atomBase + w*4 + a;
        #pragma unroll
        for (int pass = 0; pass < 2; ++pass) {
            const int s = sh + pass*2;
            const float* src = &stageF[(((w*4 + a)*4 + s) << 6)];
            unsigned int word = (unsigned int)f2bf(src[2*wi])
                              | ((unsigned int)f2bf(src[2*wi + 1]) << 16);
            Tb[(size_t)atom*128 + s*32 + wi] = word;
        }
    }
}

// 250 blocks x 512 threads (8 waves). PURE-DS inner loop (r20 proven);
// epilogue accumulates per-structure partials in LDS, then ~3 global atomics
// per block into the pre-zeroed out.
__global__ __launch_bounds__(512) void mix_kernel(
    const unsigned int* __restrict__ Tb,
    const float* __restrict__ W2p,
    const float* __restrict__ emb2,
    const float* __restrict__ w_out,
    const float* __restrict__ comp_weights,
    const float* __restrict__ scaling,
    const int* __restrict__ species,
    const int* __restrict__ batch_seg,
    float* __restrict__ out)
{
    const int tid  = threadIdx.x;
    const int w    = tid >> 6;
    const int lane = tid & 63;
    __shared__ float2 Wl[5120];        // 80 rows x 64 lanes, 40 KB
    __shared__ unsigned int TlS[5120]; // 40 atoms x 128 words, 20 KB
    __shared__ float sacc[128];

    if (tid < 128) sacc[tid] = 0.0f;
    const float2* Wg = (const float2*)W2p;
    #pragma unroll
    for (int k = 0; k < 10; ++k) Wl[k*512 + tid] = Wg[k*512 + tid];
    const unsigned int* Tsrc = Tb + (size_t)blockIdx.x * 40 * 128;
    #pragma unroll
    for (int k = 0; k < 10; ++k) TlS[k*512 + tid] = Tsrc[k*512 + tid];
    __syncthreads();

    const float scal = scaling[0];
    const int atom0 = blockIdx.x * 40 + w * 5;

    #pragma unroll 1
    for (int i = 0; i < 5; ++i) {
        const int atom = atom0 + i;
        const unsigned int* tb = &TlS[(w*5 + i) * 128];

        float aa0_0 = 0.f, aa0_1 = 0.f;
        float b1_0[3] = {0.f,0.f,0.f},           b1_1[3] = {0.f,0.f,0.f};
        float b2_0[5] = {0.f,0.f,0.f,0.f,0.f},   b2_1[5] = {0.f,0.f,0.f,0.f,0.f};
        float b3_0[7] = {0.f,0.f,0.f,0.f,0.f,0.f,0.f};
        float b3_1[7] = {0.f,0.f,0.f,0.f,0.f,0.f,0.f};

        #pragma unroll
        for (int s = 0; s < 4; ++s) {
            const unsigned int* ts = tb + s * 32;   // LDS, uniform addr -> broadcast
            #pragma unroll
            for (int n = 0; n < 8; ++n) {
                float tv = tval(ts, n);
                float2 wv = Wl[(s*8+n)*64 + lane];
                aa0_0 = fmaf(wv.x, tv, aa0_0);
                aa0_1 = fmaf(wv.y, tv, aa0_1);
            }
            #pragma unroll
            for (int n = 0; n < 6; ++n) {
                float2 wv = Wl[(32 + s*6+n)*64 + lane];
                #pragma unroll
                for (int m = 0; m < 3; ++m) {
                    float tv = tval(ts, 8 + n*3 + m);
                    b1_0[m] = fmaf(wv.x, tv, b1_0[m]);
                    b1_1[m] = fmaf(wv.y, tv, b1_1[m]);
                }
            }
            #pragma unroll
            for (int n = 0; n < 4; ++n) {
                float2 wv = Wl[(56 + s*4+n)*64 + lane];
                #pragma unroll
                for (int m = 0; m < 5; ++m) {
                    float tv = tval(ts, 28 + n*5 + m);
                    b2_0[m] = fmaf(wv.x, tv, b2_0[m]);
                    b2_1[m] = fmaf(wv.y, tv, b2_1[m]);
                }
            }
            #pragma unroll
            for (int n = 0; n < 2; ++n) {
                float2 wv = Wl[(72 + s*2+n)*64 + lane];
                #pragma unroll
                for (int m = 0; m < 7; ++m) {
                    float tv = tval(ts, 48 + n*7 + m);
                    b3_0[m] = fmaf(wv.x, tv, b3_0[m]);
                    b3_1[m] = fmaf(wv.y, tv, b3_1[m]);
                }
            }
        }

        float Bj0 = aa0_0 * aa0_0;
        float Bj1 = aa0_1 * aa0_1;
        Bj0 += (b1_0[0]*b1_0[0] + b1_0[1]*b1_0[1] + b1_0[2]*b1_0[2]) * 0.57735026918962576f;
        Bj1 += (b1_1[0]*b1_1[0] + b1_1[1]*b1_1[1] + b1_1[2]*b1_1[2]) * 0.57735026918962576f;
        {
            float s0 = 0.f, s1v = 0.f;
            #pragma unroll
            for (int m = 0; m < 5; ++m) { s0 = fmaf(b2_0[m], b2_0[m], s0); s1v = fmaf(b2_1[m], b2_1[m], s1v); }
            Bj0 += s0 * 0.44721359549995794f;
            Bj1 += s1v * 0.44721359549995794f;
        }
        {
            float s0 = 0.f, s1v = 0.f;
            #pragma unroll
            for (int m = 0; m < 7; ++m) { s0 = fmaf(b3_0[m], b3_0[m], s0); s1v = fmaf(b3_1[m], b3_1[m], s1v); }
            Bj0 += s0 * 0.37796447300922725f;
            Bj1 += s1v * 0.37796447300922725f;
        }

        const int sp = species[atom];
        float v = Bj0 * Bj0 * emb2[sp*128 + lane] * w_out[lane]
                + Bj1 * Bj1 * emb2[sp*128 + lane + 64] * w_out[lane + 64];

        #pragma unroll
        for (int o = 32; o > 0; o >>= 1) v += __shfl_down(v, o, 64);
        if (lane == 0)
            atomicAdd(&sacc[batch_seg[atom]], fmaf(v, scal, comp_weights[sp]));
    }

    __syncthreads();
    if (tid < 128) {
        float p = sacc[tid];
        if (p != 0.0f) atomicAdd(&out[tid], p);
    }
}

extern "C" void kernel_launch(void* const* d_in, const int* in_sizes, int n_in,
                              void* d_out, int out_size, void* d_ws, size_t ws_size,
                              hipStream_t stream)
{
    const float* pos  = (const float*)d_in[0];
    const float* emb  = (const float*)d_in[1];
    const float* wr0  = (const float*)d_in[2];
    const float* wm0  = (const float*)d_in[3];
    const float* wr1  = (const float*)d_in[4];
    const float* wm1  = (const float*)d_in[5];
    const float* wr2  = (const float*)d_in[6];
    const float* wm2  = (const float*)d_in[7];
    const float* wr3  = (const float*)d_in[8];
    const float* wm3  = (const float*)d_in[9];
    const float* emb2 = (const float*)d_in[10];
    const float* wout = (const float*)d_in[11];
    const float* cw   = (const float*)d_in[12];
    const float* scal = (const float*)d_in[13];
    const int* species   = (const int*)d_in[14];
    const int* senders   = (const int*)d_in[15];
    const int* receivers = (const int*)d_in[16];
    const int* batch_seg = (const int*)d_in[17];

    int* counts    = (int*)d_ws;                  // 40064
    int* offsets   = counts + 40064;              // 40064 (needs 40001)
    int* rank      = offsets + 40064;             // 200000
    int* blocksums = rank + 200000;               // 64
    int* csr       = blocksums + 64;              // 200000
    float* W2p     = (float*)(csr + 200000);      // 10240 floats
    unsigned int* Tb = (unsigned int*)(W2p + 10240); // 10000*128 uints = 5.12 MB

    zero_kernel<<<SCAN_BLOCKS, 1024, 0, stream>>>(counts, (float*)d_out, out_size);
    prep_count_kernel<<<40 + (NEDGES + 255)/256, 256, 0, stream>>>(
        emb, wm0, wm1, wm2, wm3, W2p, receivers, senders, species, counts, rank);
    scan1_kernel<<<SCAN_BLOCKS, 1024, 0, stream>>>(counts, offsets, blocksums);
    scan3_kernel<<<SCAN_BLOCKS, 1024, 0, stream>>>(offsets, blocksums);
    scatter_kernel<<<(NEDGES + 255)/256, 256, 0, stream>>>(
        receivers, senders, species, offsets, rank, csr);
    edge_tbuild_kernel<<<NATOMS/16, 256, 0, stream>>>(
        pos, wr0, wr1, wr2, wr3, senders, receivers, csr, offsets, Tb);
    mix_kernel<<<250, 512, 0, stream>>>(
        Tb, W2p, emb2, wout, cw, scal, species, batch_seg, (float*)d_out);
}

// Round 32
// 62.939 us; speedup vs baseline: 1.4162x; 1.0216x over previous
//
#include <hip/hip_runtime.h>
#include <math.h>

#define NATOMS 10000
#define NEDGES 200000
#define NBINS  40000   // (receiver, species) bins = NATOMS*4
#define SCAN_BLOCKS 40 // 40*1024 >= NBINS

// CSR sorted by (receiver, species); entry = packed (snd | rcv<<16).
// T tile per atom: 256 bf16 (4 species x 64 PADDED slots), stored as 128 uints.
// word k of species s = slots (2k, 2k+1); slot order l0@0, l1@8, l2@28, l3@48;
// pads at 26,27,62,63 (zeroed). even slot -> low 16 bits.
// W2p layout: 80 rows x 64 float2; row = lbase + s*Nl + n, lbase l0@0,l1@32,l2@56,l3@72.
// float2 = (channel j, channel j+64) for lane j.

__device__ __forceinline__ unsigned short f2bf(float f) {
    unsigned int u = __float_as_uint(f);
    u += 0x7FFFu + ((u >> 16) & 1u);   // round-to-nearest-even
    return (unsigned short)(u >> 16);
}

__device__ __forceinline__ float bf2f(unsigned short h) {
    return __uint_as_float(((unsigned int)h) << 16);
}

// unpack slot idx from a 32-word bf16 species row (LDS or global)
__device__ __forceinline__ float tval(const unsigned int* ts, int idx) {
    unsigned int u = ts[idx >> 1];
    return __uint_as_float((idx & 1) ? (u & 0xFFFF0000u) : (u << 16));
}

// Parallel zero of counts AND d_out (runtime fillBuffer is pathologically slow).
__global__ __launch_bounds__(1024) void zero_kernel(
    int* __restrict__ counts, float* __restrict__ out, int out_size)
{
    int i = blockIdx.x * 1024 + threadIdx.x;
    if (i < NBINS) counts[i] = 0;
    if (blockIdx.x == 0 && threadIdx.x < out_size) out[threadIdx.x] = 0.0f;
}

// blocks [0,40): prep W2p. rest: count edges AND record each edge's rank
// within its bin (the counting atomic's return value) -> atomic-free scatter.
__global__ __launch_bounds__(256) void prep_count_kernel(
    const float* __restrict__ emb,
    const float* __restrict__ wm0, const float* __restrict__ wm1,
    const float* __restrict__ wm2, const float* __restrict__ wm3,
    float* __restrict__ W2p,
    const int* __restrict__ receivers, const int* __restrict__ senders,
    const int* __restrict__ species, int* __restrict__ counts,
    int* __restrict__ rank)
{
    if (blockIdx.x < 40) {
        int tid = blockIdx.x * 256 + threadIdx.x;
        if (tid >= 10240) return;
        const float* wm; int idx, Nl, lbase;
        if (tid < 4096)      { wm = wm0; idx = tid;        Nl = 8; lbase = 0;  }
        else if (tid < 7168) { wm = wm1; idx = tid - 4096; Nl = 6; lbase = 32; }
        else if (tid < 9216) { wm = wm2; idx = tid - 7168; Nl = 4; lbase = 56; }
        else                 { wm = wm3; idx = tid - 9216; Nl = 2; lbase = 72; }
        int j  = idx & 127;
        int sn = idx >> 7;
        int n  = sn % Nl;
        float acc = 0.0f;
        #pragma unroll
        for (int c = 0; c < 16; ++c)
            acc = fmaf(wm[(n*16 + c)*128 + j], emb[(sn / Nl)*16 + c], acc);
        int row = lbase + sn;
        W2p[(row*64 + (j & 63))*2 + (j >> 6)] = acc;
    } else {
        int e = (blockIdx.x - 40) * 256 + threadIdx.x;
        if (e < NEDGES) {
            int key = receivers[e] * 4 + species[senders[e]];
            rank[e] = atomicAdd(&counts[key], 1);
        }
    }
}

__global__ __launch_bounds__(1024) void scan1_kernel(
    const int* __restrict__ counts, int* __restrict__ offsets,
    int* __restrict__ blocksums)
{
    __shared__ int sh[1024];
    const int t = threadIdx.x;
    const int idx = blockIdx.x * 1024 + t;
    const int v = (idx < NBINS) ? counts[idx] : 0;
    sh[t] = v;
    __syncthreads();
    for (int off = 1; off < 1024; off <<= 1) {
        int u = (t >= off) ? sh[t - off] : 0;
        __syncthreads();
        sh[t] += u;
        __syncthreads();
    }
    if (idx < NBINS) offsets[idx] = sh[t] - v;   // block-local exclusive
    if (t == 1023) blocksums[blockIdx.x] = sh[1023];
}

// scan2 folded in: each block sums blocksums[0..bid) itself.
__global__ __launch_bounds__(1024) void scan3_kernel(
    int* __restrict__ offsets, const int* __restrict__ blocksums)
{
    __shared__ int sbase;
    if (threadIdx.x == 0) {
        int b = 0;
        for (int k = 0; k < (int)blockIdx.x; ++k) b += blocksums[k];
        sbase = b;
    }
    __syncthreads();
    const int idx = blockIdx.x * 1024 + threadIdx.x;
    if (idx < NBINS) offsets[idx] += sbase;
    if (idx == 0) offsets[NBINS] = NEDGES;
}

// Atomic-free scatter: destination = offsets[key] + rank[e].
// Stores PACKED endpoints (snd | rcv<<16) so edge_tbuild needs no gathers.
__global__ __launch_bounds__(256) void scatter_kernel(
    const int* __restrict__ receivers, const int* __restrict__ senders,
    const int* __restrict__ species, const int* __restrict__ offsets,
    const int* __restrict__ rank, unsigned int* __restrict__ csr)
{
    int e = blockIdx.x * 256 + threadIdx.x;
    if (e < NEDGES) {
        int snd = senders[e];
        int rcv = receivers[e];
        int key = rcv * 4 + species[snd];
        csr[offsets[key] + rank[e]] =
            (unsigned int)snd | ((unsigned int)rcv << 16);
    }
}

// FUSED edge-math + T-build. 625 blocks x 256 threads; block owns 16 atoms.
// Output T is packed bf16 (128 uints/atom) via in-LDS staging transpose.
__global__ __launch_bounds__(256) void edge_tbuild_kernel(
    const float* __restrict__ pos,
    const float* __restrict__ wr0, const float* __restrict__ wr1,
    const float* __restrict__ wr2, const float* __restrict__ wr3,
    const unsigned int* __restrict__ csr,
    const int* __restrict__ off4,
    unsigned int* __restrict__ Tb)
{
    const int tid  = threadIdx.x;
    const int w    = tid >> 6;
    const int lane = tid & 63;
    const int atomBase = blockIdx.x * 16;
    __shared__ unsigned int raw32[256 * 31];   // 31744 B, stride-31 rows

    int bnd[4][5];
    #pragma unroll
    for (int a = 0; a < 4; ++a)
        #pragma unroll
        for (int s = 0; s < 5; ++s)
            bnd[a][s] = off4[(atomBase + w*4 + a)*4 + s];
    const int blockBeg = off4[atomBase*4];
    const int blockEnd = off4[atomBase*4 + 64];

    float acc[4][4];
    #pragma unroll
    for (int a = 0; a < 4; ++a)
        #pragma unroll
        for (int s = 0; s < 4; ++s) acc[a][s] = 0.0f;

    const int dw   = lane >> 1;            // dword 0..29 (lanes 0..59)
    const int half = lane & 1;

    for (int c = blockBeg; c < blockEnd; c += 256) {
        const int i = c + tid;
        if (i < blockEnd) {
            const unsigned int pk = csr[i];
            const int snd = (int)(pk & 0xFFFFu);
            const int rcv = (int)(pk >> 16);

            float dx = pos[rcv*3]   - pos[snd*3];
            float dy = pos[rcv*3+1] - pos[snd*3+1];
            float dz = pos[rcv*3+2] - pos[snd*3+2];
            float r = sqrtf(dx*dx + dy*dy + dz*dz + 1e-12f);
            float inv_r = 1.0f / r;
            float x = dx * inv_r, y = dy * inv_r, z = dz * inv_r;

            float xr = fminf(r * 0.2f, 1.0f);
            float s1, c1;
            sincosf(3.14159265358979323846f * xr, &s1, &c1);
            float fcut = 0.5f * (c1 + 1.0f);
            float g = fcut / (xr + 0.001f);

            float bess[8];
            {
                float sm1 = 0.0f, s0 = s1;
                float tc = 2.0f * c1;
                #pragma unroll
                for (int n = 0; n < 8; ++n) {
                    bess[n] = s0 * g;
                    float s2 = tc * s0 - sm1;
                    sm1 = s0; s0 = s2;
                }
            }

            float R0[8], R1[6], R2[4], R3[2];
            #pragma unroll
            for (int n = 0; n < 8; ++n) R0[n] = 0.0f;
            #pragma unroll
            for (int n = 0; n < 6; ++n) R1[n] = 0.0f;
            #pragma unroll
            for (int n = 0; n < 4; ++n) R2[n] = 0.0f;
            #pragma unroll
            for (int n = 0; n < 2; ++n) R3[n] = 0.0f;
            #pragma unroll
            for (int k = 0; k < 8; ++k) {
                float b = bess[k];
                #pragma unroll
                for (int n = 0; n < 8; ++n) R0[n] = fmaf(b, wr0[k*8 + n], R0[n]);
                #pragma unroll
                for (int n = 0; n < 6; ++n) R1[n] = fmaf(b, wr1[k*6 + n], R1[n]);
                #pragma unroll
                for (int n = 0; n < 4; ++n) R2[n] = fmaf(b, wr2[k*4 + n], R2[n]);
                #pragma unroll
                for (int n = 0; n < 2; ++n) R3[n] = fmaf(b, wr3[k*2 + n], R3[n]);
            }

            float xy = x*y, yz = y*z, xz = x*z;
            float x2 = x*x, y2 = y*y, z2 = z*z;
            float sh1v[3] = {0.4886025119029199f*y, 0.4886025119029199f*z, 0.4886025119029199f*x};
            float sh2v[5] = {1.0925484305920792f*xy, 1.0925484305920792f*yz,
                             0.31539156525252005f*(3.0f*z2 - 1.0f),
                             1.0925484305920792f*xz, 0.5462742152960396f*(x2 - y2)};
            float sh3v[7] = {0.5900435899266435f*y*(3.0f*x2 - y2),
                             2.890611442640554f*xy*z,
                             0.4570457994644658f*y*(5.0f*z2 - 1.0f),
                             0.3731763325901154f*z*(5.0f*z2 - 3.0f),
                             0.4570457994644658f*x*(5.0f*z2 - 1.0f),
                             1.445305721320277f*z*(x2 - y2),
                             0.5900435899266435f*x*(x2 - 3.0f*y2)};

            unsigned short h[60];
            #pragma unroll
            for (int n = 0; n < 8; ++n)
                h[n] = f2bf(R0[n] * 0.28209479177387814f);
            #pragma unroll
            for (int n = 0; n < 6; ++n)
                #pragma unroll
                for (int m = 0; m < 3; ++m)
                    h[8 + n*3 + m] = f2bf(R1[n] * sh1v[m]);
            #pragma unroll
            for (int n = 0; n < 4; ++n)
                #pragma unroll
                for (int m = 0; m < 5; ++m)
                    h[26 + n*5 + m] = f2bf(R2[n] * sh2v[m]);
            #pragma unroll
            for (int n = 0; n < 2; ++n)
                #pragma unroll
                for (int m = 0; m < 7; ++m)
                    h[46 + n*7 + m] = f2bf(R3[n] * sh3v[m]);

            unsigned int* dst = &raw32[tid * 31];
            #pragma unroll
            for (int k = 0; k < 30; ++k)
                dst[k] = (unsigned int)h[2*k] | ((unsigned int)h[2*k+1] << 16);
        }
        __syncthreads();

        const int n = (blockEnd - c < 256) ? (blockEnd - c) : 256;
        if (lane < 60) {
            #pragma unroll
            for (int a = 0; a < 4; ++a) {
                #pragma unroll
                for (int s = 0; s < 4; ++s) {
                    const int lo = (bnd[a][s]   > c     ? bnd[a][s]   : c)     - c;
                    const int hi = (bnd[a][s+1] < c + n ? bnd[a][s+1] : c + n) - c;
                    float v = acc[a][s];
                    for (int r = lo; r < hi; ++r) {
                        unsigned int u = raw32[r*31 + dw];
                        v += bf2f(half ? (unsigned short)(u >> 16)
                                       : (unsigned short)(u & 0xFFFFu));
                    }
                    acc[a][s] = v;
                }
            }
        }
        __syncthreads();   // before next chunk overwrites raw32
    }

    // ---- pack T to bf16 via LDS staging (reuse raw32 as float stage) ----
    float* stageF = (float*)raw32;   // [w][a][s][64] floats = 16 KB
    const int pl = lane + (lane >= 26 ? 2 : 0);   // packed->padded
    if (lane < 60) {
        #pragma unroll
        for (int a = 0; a < 4; ++a)
            #pragma unroll
            for (int s = 0; s < 4; ++s)
                stageF[(((w*4 + a)*4 + s) << 6) + pl] = acc[a][s];
    } else {
        int p = lane - 60;
        int pi = (p < 2) ? (26 + p) : (62 + (p - 2));
        #pragma unroll
        for (int a = 0; a < 4; ++a)
            #pragma unroll
            for (int s = 0; s < 4; ++s)
                stageF[(((w*4 + a)*4 + s) << 6) + pi] = 0.0f;
    }
    __syncthreads();

    const int wi = lane & 31;        // word index within species row
    const int sh = lane >> 5;        // 0/1
    #pragma unroll
    for (int a = 0; a < 4; ++a) {
        const int atom = atomBase + w*4 + a;
        #pragma unroll
        for (int pass = 0; pass < 2; ++pass) {
            const int s = sh + pass*2;
            const float* src = &stageF[(((w*4 + a)*4 + s) << 6)];
            unsigned int word = (unsigned int)f2bf(src[2*wi])
                              | ((unsigned int)f2bf(src[2*wi + 1]) << 16);
            Tb[(size_t)atom*128 + s*32 + wi] = word;
        }
    }
}

// 250 blocks x 512 threads (8 waves). PURE-DS inner loop (r20 proven);
// epilogue accumulates per-structure partials in LDS, then ~3 global atomics
// per block into the pre-zeroed out.
__global__ __launch_bounds__(512) void mix_kernel(
    const unsigned int* __restrict__ Tb,
    const float* __restrict__ W2p,
    const float* __restrict__ emb2,
    const float* __restrict__ w_out,
    const float* __restrict__ comp_weights,
    const float* __restrict__ scaling,
    const int* __restrict__ species,
    const int* __restrict__ batch_seg,
    float* __restrict__ out)
{
    const int tid  = threadIdx.x;
    const int w    = tid >> 6;
    const int lane = tid & 63;
    __shared__ float2 Wl[5120];        // 80 rows x 64 lanes, 40 KB
    __shared__ unsigned int TlS[5120]; // 40 atoms x 128 words, 20 KB
    __shared__ float sacc[128];

    if (tid < 128) sacc[tid] = 0.0f;
    const float2* Wg = (const float2*)W2p;
    #pragma unroll
    for (int k = 0; k < 10; ++k) Wl[k*512 + tid] = Wg[k*512 + tid];
    const unsigned int* Tsrc = Tb + (size_t)blockIdx.x * 40 * 128;
    #pragma unroll
    for (int k = 0; k < 10; ++k) TlS[k*512 + tid] = Tsrc[k*512 + tid];
    __syncthreads();

    const float scal = scaling[0];
    const int atom0 = blockIdx.x * 40 + w * 5;

    #pragma unroll 1
    for (int i = 0; i < 5; ++i) {
        const int atom = atom0 + i;
        const unsigned int* tb = &TlS[(w*5 + i) * 128];

        float aa0_0 = 0.f, aa0_1 = 0.f;
        float b1_0[3] = {0.f,0.f,0.f},           b1_1[3] = {0.f,0.f,0.f};
        float b2_0[5] = {0.f,0.f,0.f,0.f,0.f},   b2_1[5] = {0.f,0.f,0.f,0.f,0.f};
        float b3_0[7] = {0.f,0.f,0.f,0.f,0.f,0.f,0.f};
        float b3_1[7] = {0.f,0.f,0.f,0.f,0.f,0.f,0.f};

        #pragma unroll
        for (int s = 0; s < 4; ++s) {
            const unsigned int* ts = tb + s * 32;   // LDS, uniform addr -> broadcast
            #pragma unroll
            for (int n = 0; n < 8; ++n) {
                float tv = tval(ts, n);
                float2 wv = Wl[(s*8+n)*64 + lane];
                aa0_0 = fmaf(wv.x, tv, aa0_0);
                aa0_1 = fmaf(wv.y, tv, aa0_1);
            }
            #pragma unroll
            for (int n = 0; n < 6; ++n) {
                float2 wv = Wl[(32 + s*6+n)*64 + lane];
                #pragma unroll
                for (int m = 0; m < 3; ++m) {
                    float tv = tval(ts, 8 + n*3 + m);
                    b1_0[m] = fmaf(wv.x, tv, b1_0[m]);
                    b1_1[m] = fmaf(wv.y, tv, b1_1[m]);
                }
            }
            #pragma unroll
            for (int n = 0; n < 4; ++n) {
                float2 wv = Wl[(56 + s*4+n)*64 + lane];
                #pragma unroll
                for (int m = 0; m < 5; ++m) {
                    float tv = tval(ts, 28 + n*5 + m);
                    b2_0[m] = fmaf(wv.x, tv, b2_0[m]);
                    b2_1[m] = fmaf(wv.y, tv, b2_1[m]);
                }
            }
            #pragma unroll
            for (int n = 0; n < 2; ++n) {
                float2 wv = Wl[(72 + s*2+n)*64 + lane];
                #pragma unroll
                for (int m = 0; m < 7; ++m) {
                    float tv = tval(ts, 48 + n*7 + m);
                    b3_0[m] = fmaf(wv.x, tv, b3_0[m]);
                    b3_1[m] = fmaf(wv.y, tv, b3_1[m]);
                }
            }
        }

        float Bj0 = aa0_0 * aa0_0;
        float Bj1 = aa0_1 * aa0_1;
        Bj0 += (b1_0[0]*b1_0[0] + b1_0[1]*b1_0[1] + b1_0[2]*b1_0[2]) * 0.57735026918962576f;
        Bj1 += (b1_1[0]*b1_1[0] + b1_1[1]*b1_1[1] + b1_1[2]*b1_1[2]) * 0.57735026918962576f;
        {
            float s0 = 0.f, s1v = 0.f;
            #pragma unroll
            for (int m = 0; m < 5; ++m) { s0 = fmaf(b2_0[m], b2_0[m], s0); s1v = fmaf(b2_1[m], b2_1[m], s1v); }
            Bj0 += s0 * 0.44721359549995794f;
            Bj1 += s1v * 0.44721359549995794f;
        }
        {
            float s0 = 0.f, s1v = 0.f;
            #pragma unroll
            for (int m = 0; m < 7; ++m) { s0 = fmaf(b3_0[m], b3_0[m], s0); s1v = fmaf(b3_1[m], b3_1[m], s1v); }
            Bj0 += s0 * 0.37796447300922725f;
            Bj1 += s1v * 0.37796447300922725f;
        }

        const int sp = species[atom];
        float v = Bj0 * Bj0 * emb2[sp*128 + lane] * w_out[lane]
                + Bj1 * Bj1 * emb2[sp*128 + lane + 64] * w_out[lane + 64];

        #pragma unroll
        for (int o = 32; o > 0; o >>= 1) v += __shfl_down(v, o, 64);
        if (lane == 0)
            atomicAdd(&sacc[batch_seg[atom]], fmaf(v, scal, comp_weights[sp]));
    }

    __syncthreads();
    if (tid < 128) {
        float p = sacc[tid];
        if (p != 0.0f) atomicAdd(&out[tid], p);
    }
}

extern "C" void kernel_launch(void* const* d_in, const int* in_sizes, int n_in,
                              void* d_out, int out_size, void* d_ws, size_t ws_size,
                              hipStream_t stream)
{
    const float* pos  = (const float*)d_in[0];
    const float* emb  = (const float*)d_in[1];
    const float* wr0  = (const float*)d_in[2];
    const float* wm0  = (const float*)d_in[3];
    const float* wr1  = (const float*)d_in[4];
    const float* wm1  = (const float*)d_in[5];
    const float* wr2  = (const float*)d_in[6];
    const float* wm2  = (const float*)d_in[7];
    const float* wr3  = (const float*)d_in[8];
    const float* wm3  = (const float*)d_in[9];
    const float* emb2 = (const float*)d_in[10];
    const float* wout = (const float*)d_in[11];
    const float* cw   = (const float*)d_in[12];
    const float* scal = (const float*)d_in[13];
    const int* species   = (const int*)d_in[14];
    const int* senders   = (const int*)d_in[15];
    const int* receivers = (const int*)d_in[16];
    const int* batch_seg = (const int*)d_in[17];

    int* counts    = (int*)d_ws;                  // 40064
    int* offsets   = counts + 40064;              // 40064 (needs 40001)
    int* rank      = offsets + 40064;             // 200000
    int* blocksums = rank + 200000;               // 64
    unsigned int* csr = (unsigned int*)(blocksums + 64); // 200000
    float* W2p     = (float*)(csr + 200000);      // 10240 floats
    unsigned int* Tb = (unsigned int*)(W2p + 10240); // 10000*128 uints = 5.12 MB

    zero_kernel<<<SCAN_BLOCKS, 1024, 0, stream>>>(counts, (float*)d_out, out_size);
    prep_count_kernel<<<40 + (NEDGES + 255)/256, 256, 0, stream>>>(
        emb, wm0, wm1, wm2, wm3, W2p, receivers, senders, species, counts, rank);
    scan1_kernel<<<SCAN_BLOCKS, 1024, 0, stream>>>(counts, offsets, blocksums);
    scan3_kernel<<<SCAN_BLOCKS, 1024, 0, stream>>>(offsets, blocksums);
    scatter_kernel<<<(NEDGES + 255)/256, 256, 0, stream>>>(
        receivers, senders, species, offsets, rank, csr);
    edge_tbuild_kernel<<<NATOMS/16, 256, 0, stream>>>(
        pos, wr0, wr1, wr2, wr3, csr, offsets, Tb);
    mix_kernel<<<250, 512, 0, stream>>>(
        Tb, W2p, emb2, wout, cw, scal, species, batch_seg, (float*)d_out);
}

// Round 33
// 62.427 us; speedup vs baseline: 1.4278x; 1.0082x over previous
//
#include <hip/hip_runtime.h>
#include <math.h>

#define NATOMS 10000
#define NEDGES 200000
#define NBINS  40000   // (receiver, species) bins = NATOMS*4
#define SCAN_BLOCKS 40 // 40*1024 >= NBINS

// CSR sorted by (receiver, species); entry = packed (snd | rcv<<16).
// offsets[] holds BLOCK-LOCAL exclusive sums; consumers add the 40-entry
// block prefix (from blocksums) themselves -> no scan3 pass.
// T tile per atom: 256 bf16 (4 species x 64 PADDED slots), stored as 128 uints.
// W2p layout: 80 rows x 64 float2; row = lbase + s*Nl + n, lbase l0@0,l1@32,l2@56,l3@72.

__device__ __forceinline__ unsigned short f2bf(float f) {
    unsigned int u = __float_as_uint(f);
    u += 0x7FFFu + ((u >> 16) & 1u);   // round-to-nearest-even
    return (unsigned short)(u >> 16);
}

__device__ __forceinline__ float bf2f(unsigned short h) {
    return __uint_as_float(((unsigned int)h) << 16);
}

// unpack slot idx from a 32-word bf16 species row (LDS or global)
__device__ __forceinline__ float tval(const unsigned int* ts, int idx) {
    unsigned int u = ts[idx >> 1];
    return __uint_as_float((idx & 1) ? (u & 0xFFFF0000u) : (u << 16));
}

// Parallel zero of counts AND d_out (runtime fillBuffer is pathologically slow).
__global__ __launch_bounds__(1024) void zero_kernel(
    int* __restrict__ counts, float* __restrict__ out, int out_size)
{
    int i = blockIdx.x * 1024 + threadIdx.x;
    if (i < NBINS) counts[i] = 0;
    if (blockIdx.x == 0 && threadIdx.x < out_size) out[threadIdx.x] = 0.0f;
}

// blocks [0,40): prep W2p. rest: count edges AND record each edge's rank
// within its bin (the counting atomic's return value) -> atomic-free scatter.
__global__ __launch_bounds__(256) void prep_count_kernel(
    const float* __restrict__ emb,
    const float* __restrict__ wm0, const float* __restrict__ wm1,
    const float* __restrict__ wm2, const float* __restrict__ wm3,
    float* __restrict__ W2p,
    const int* __restrict__ receivers, const int* __restrict__ senders,
    const int* __restrict__ species, int* __restrict__ counts,
    int* __restrict__ rank)
{
    if (blockIdx.x < 40) {
        int tid = blockIdx.x * 256 + threadIdx.x;
        if (tid >= 10240) return;
        const float* wm; int idx, Nl, lbase;
        if (tid < 4096)      { wm = wm0; idx = tid;        Nl = 8; lbase = 0;  }
        else if (tid < 7168) { wm = wm1; idx = tid - 4096; Nl = 6; lbase = 32; }
        else if (tid < 9216) { wm = wm2; idx = tid - 7168; Nl = 4; lbase = 56; }
        else                 { wm = wm3; idx = tid - 9216; Nl = 2; lbase = 72; }
        int j  = idx & 127;
        int sn = idx >> 7;
        int n  = sn % Nl;
        float acc = 0.0f;
        #pragma unroll
        for (int c = 0; c < 16; ++c)
            acc = fmaf(wm[(n*16 + c)*128 + j], emb[(sn / Nl)*16 + c], acc);
        int row = lbase + sn;
        W2p[(row*64 + (j & 63))*2 + (j >> 6)] = acc;
    } else {
        int e = (blockIdx.x - 40) * 256 + threadIdx.x;
        if (e < NEDGES) {
            int key = receivers[e] * 4 + species[senders[e]];
            rank[e] = atomicAdd(&counts[key], 1);
        }
    }
}

__global__ __launch_bounds__(1024) void scan1_kernel(
    const int* __restrict__ counts, int* __restrict__ offsets,
    int* __restrict__ blocksums)
{
    __shared__ int sh[1024];
    const int t = threadIdx.x;
    const int idx = blockIdx.x * 1024 + t;
    const int v = (idx < NBINS) ? counts[idx] : 0;
    sh[t] = v;
    __syncthreads();
    for (int off = 1; off < 1024; off <<= 1) {
        int u = (t >= off) ? sh[t - off] : 0;
        __syncthreads();
        sh[t] += u;
        __syncthreads();
    }
    if (idx < NBINS) offsets[idx] = sh[t] - v;   // block-local exclusive
    if (t == 1023) blocksums[blockIdx.x] = sh[1023];
}

// Atomic-free scatter: destination = offsets[key] + sb[key>>10] + rank[e].
// Stores PACKED endpoints (snd | rcv<<16) so edge_tbuild needs no gathers.
__global__ __launch_bounds__(256) void scatter_kernel(
    const int* __restrict__ receivers, const int* __restrict__ senders,
    const int* __restrict__ species, const int* __restrict__ offsets,
    const int* __restrict__ blocksums,
    const int* __restrict__ rank, unsigned int* __restrict__ csr)
{
    __shared__ int sb[SCAN_BLOCKS];
    if (threadIdx.x == 0) {
        int run = 0;
        for (int k = 0; k < SCAN_BLOCKS; ++k) { sb[k] = run; run += blocksums[k]; }
    }
    __syncthreads();
    int e = blockIdx.x * 256 + threadIdx.x;
    if (e < NEDGES) {
        int snd = senders[e];
        int rcv = receivers[e];
        int key = rcv * 4 + species[snd];
        csr[offsets[key] + sb[key >> 10] + rank[e]] =
            (unsigned int)snd | ((unsigned int)rcv << 16);
    }
}

// FUSED edge-math + T-build. 625 blocks x 256 threads; block owns 16 atoms.
// Output T is packed bf16 (128 uints/atom) via in-LDS staging transpose.
__global__ __launch_bounds__(256) void edge_tbuild_kernel(
    const float* __restrict__ pos,
    const float* __restrict__ wr0, const float* __restrict__ wr1,
    const float* __restrict__ wr2, const float* __restrict__ wr3,
    const unsigned int* __restrict__ csr,
    const int* __restrict__ off4,
    const int* __restrict__ blocksums,
    unsigned int* __restrict__ Tb)
{
    const int tid  = threadIdx.x;
    const int w    = tid >> 6;
    const int lane = tid & 63;
    const int atomBase = blockIdx.x * 16;
    __shared__ unsigned int raw32[256 * 31];   // 31744 B, stride-31 rows
    __shared__ int sb[SCAN_BLOCKS];

    if (tid == 0) {
        int run = 0;
        for (int k = 0; k < SCAN_BLOCKS; ++k) { sb[k] = run; run += blocksums[k]; }
    }
    __syncthreads();

    int bnd[4][5];
    #pragma unroll
    for (int a = 0; a < 4; ++a)
        #pragma unroll
        for (int s = 0; s < 5; ++s) {
            const int idx = (atomBase + w*4 + a)*4 + s;
            bnd[a][s] = (idx >= NBINS) ? NEDGES : off4[idx] + sb[idx >> 10];
        }
    const int bb_idx = atomBase*4;
    const int be_idx = atomBase*4 + 64;
    const int blockBeg = off4[bb_idx] + sb[bb_idx >> 10];
    const int blockEnd = (be_idx >= NBINS) ? NEDGES : off4[be_idx] + sb[be_idx >> 10];

    float acc[4][4];
    #pragma unroll
    for (int a = 0; a < 4; ++a)
        #pragma unroll
        for (int s = 0; s < 4; ++s) acc[a][s] = 0.0f;

    const int dw   = lane >> 1;            // dword 0..29 (lanes 0..59)
    const int half = lane & 1;

    for (int c = blockBeg; c < blockEnd; c += 256) {
        const int i = c + tid;
        if (i < blockEnd) {
            const unsigned int pk = csr[i];
            const int snd = (int)(pk & 0xFFFFu);
            const int rcv = (int)(pk >> 16);

            float dx = pos[rcv*3]   - pos[snd*3];
            float dy = pos[rcv*3+1] - pos[snd*3+1];
            float dz = pos[rcv*3+2] - pos[snd*3+2];
            float r = sqrtf(dx*dx + dy*dy + dz*dz + 1e-12f);
            float inv_r = 1.0f / r;
            float x = dx * inv_r, y = dy * inv_r, z = dz * inv_r;

            float xr = fminf(r * 0.2f, 1.0f);
            float s1, c1;
            sincosf(3.14159265358979323846f * xr, &s1, &c1);
            float fcut = 0.5f * (c1 + 1.0f);
            float g = fcut / (xr + 0.001f);

            float bess[8];
            {
                float sm1 = 0.0f, s0 = s1;
                float tc = 2.0f * c1;
                #pragma unroll
                for (int n = 0; n < 8; ++n) {
                    bess[n] = s0 * g;
                    float s2 = tc * s0 - sm1;
                    sm1 = s0; s0 = s2;
                }
            }

            float R0[8], R1[6], R2[4], R3[2];
            #pragma unroll
            for (int n = 0; n < 8; ++n) R0[n] = 0.0f;
            #pragma unroll
            for (int n = 0; n < 6; ++n) R1[n] = 0.0f;
            #pragma unroll
            for (int n = 0; n < 4; ++n) R2[n] = 0.0f;
            #pragma unroll
            for (int n = 0; n < 2; ++n) R3[n] = 0.0f;
            #pragma unroll
            for (int k = 0; k < 8; ++k) {
                float b = bess[k];
                #pragma unroll
                for (int n = 0; n < 8; ++n) R0[n] = fmaf(b, wr0[k*8 + n], R0[n]);
                #pragma unroll
                for (int n = 0; n < 6; ++n) R1[n] = fmaf(b, wr1[k*6 + n], R1[n]);
                #pragma unroll
                for (int n = 0; n < 4; ++n) R2[n] = fmaf(b, wr2[k*4 + n], R2[n]);
                #pragma unroll
                for (int n = 0; n < 2; ++n) R3[n] = fmaf(b, wr3[k*2 + n], R3[n]);
            }

            float xy = x*y, yz = y*z, xz = x*z;
            float x2 = x*x, y2 = y*y, z2 = z*z;
            float sh1v[3] = {0.4886025119029199f*y, 0.4886025119029199f*z, 0.4886025119029199f*x};
            float sh2v[5] = {1.0925484305920792f*xy, 1.0925484305920792f*yz,
                             0.31539156525252005f*(3.0f*z2 - 1.0f),
                             1.0925484305920792f*xz, 0.5462742152960396f*(x2 - y2)};
            float sh3v[7] = {0.5900435899266435f*y*(3.0f*x2 - y2),
                             2.890611442640554f*xy*z,
                             0.4570457994644658f*y*(5.0f*z2 - 1.0f),
                             0.3731763325901154f*z*(5.0f*z2 - 3.0f),
                             0.4570457994644658f*x*(5.0f*z2 - 1.0f),
                             1.445305721320277f*z*(x2 - y2),
                             0.5900435899266435f*x*(x2 - 3.0f*y2)};

            unsigned short h[60];
            #pragma unroll
            for (int n = 0; n < 8; ++n)
                h[n] = f2bf(R0[n] * 0.28209479177387814f);
            #pragma unroll
            for (int n = 0; n < 6; ++n)
                #pragma unroll
                for (int m = 0; m < 3; ++m)
                    h[8 + n*3 + m] = f2bf(R1[n] * sh1v[m]);
            #pragma unroll
            for (int n = 0; n < 4; ++n)
                #pragma unroll
                for (int m = 0; m < 5; ++m)
                    h[26 + n*5 + m] = f2bf(R2[n] * sh2v[m]);
            #pragma unroll
            for (int n = 0; n < 2; ++n)
                #pragma unroll
                for (int m = 0; m < 7; ++m)
                    h[46 + n*7 + m] = f2bf(R3[n] * sh3v[m]);

            unsigned int* dst = &raw32[tid * 31];
            #pragma unroll
            for (int k = 0; k < 30; ++k)
                dst[k] = (unsigned int)h[2*k] | ((unsigned int)h[2*k+1] << 16);
        }
        __syncthreads();

        const int n = (blockEnd - c < 256) ? (blockEnd - c) : 256;
        if (lane < 60) {
            #pragma unroll
            for (int a = 0; a < 4; ++a) {
                #pragma unroll
                for (int s = 0; s < 4; ++s) {
                    const int lo = (bnd[a][s]   > c     ? bnd[a][s]   : c)     - c;
                    const int hi = (bnd[a][s+1] < c + n ? bnd[a][s+1] : c + n) - c;
                    float v = acc[a][s];
                    for (int r = lo; r < hi; ++r) {
                        unsigned int u = raw32[r*31 + dw];
                        v += bf2f(half ? (unsigned short)(u >> 16)
                                       : (unsigned short)(u & 0xFFFFu));
                    }
                    acc[a][s] = v;
                }
            }
        }
        __syncthreads();   // before next chunk overwrites raw32
    }

    // ---- pack T to bf16 via LDS staging (reuse raw32 as float stage) ----
    float* stageF = (float*)raw32;   // [w][a][s][64] floats = 16 KB
    const int pl = lane + (lane >= 26 ? 2 : 0);   // packed->padded
    if (lane < 60) {
        #pragma unroll
        for (int a = 0; a < 4; ++a)
            #pragma unroll
            for (int s = 0; s < 4; ++s)
                stageF[(((w*4 + a)*4 + s) << 6) + pl] = acc[a][s];
    } else {
        int p = lane - 60;
        int pi = (p < 2) ? (26 + p) : (62 + (p - 2));
        #pragma unroll
        for (int a = 0; a < 4; ++a)
            #pragma unroll
            for (int s = 0; s < 4; ++s)
                stageF[(((w*4 + a)*4 + s) << 6) + pi] = 0.0f;
    }
    __syncthreads();

    const int wi = lane & 31;        // word index within species row
    const int sh = lane >> 5;        // 0/1
    #pragma unroll
    for (int a = 0; a < 4; ++a) {
        const int atom = atomBase + w*4 + a;
        #pragma unroll
        for (int pass = 0; pass < 2; ++pass) {
            const int s = sh + pass*2;
            const float* src = &stageF[(((w*4 + a)*4 + s) << 6)];
            unsigned int word = (unsigned int)f2bf(src[2*wi])
                              | ((unsigned int)f2bf(src[2*wi + 1]) << 16);
            Tb[(size_t)atom*128 + s*32 + wi] = word;
        }
    }
}

// 250 blocks x 512 threads (8 waves). PURE-DS inner loop (r20 proven);
// epilogue accumulates per-structure partials in LDS, then ~3 global atomics
// per block into the pre-zeroed out.
__global__ __launch_bounds__(512) void mix_kernel(
    const unsigned int* __restrict__ Tb,
    const float* __restrict__ W2p,
    const float* __restrict__ emb2,
    const float* __restrict__ w_out,
    const float* __restrict__ comp_weights,
    const float* __restrict__ scaling,
    const int* __restrict__ species,
    const int* __restrict__ batch_seg,
    float* __restrict__ out)
{
    const int tid  = threadIdx.x;
    const int w    = tid >> 6;
    const int lane = tid & 63;
    __shared__ float2 Wl[5120];        // 80 rows x 64 lanes, 40 KB
    __shared__ unsigned int TlS[5120]; // 40 atoms x 128 words, 20 KB
    __shared__ float sacc[128];

    if (tid < 128) sacc[tid] = 0.0f;
    const float2* Wg = (const float2*)W2p;
    #pragma unroll
    for (int k = 0; k < 10; ++k) Wl[k*512 + tid] = Wg[k*512 + tid];
    const unsigned int* Tsrc = Tb + (size_t)blockIdx.x * 40 * 128;
    #pragma unroll
    for (int k = 0; k < 10; ++k) TlS[k*512 + tid] = Tsrc[k*512 + tid];
    __syncthreads();

    const float scal = scaling[0];
    const int atom0 = blockIdx.x * 40 + w * 5;

    #pragma unroll 1
    for (int i = 0; i < 5; ++i) {
        const int atom = atom0 + i;
        const unsigned int* tb = &TlS[(w*5 + i) * 128];

        float aa0_0 = 0.f, aa0_1 = 0.f;
        float b1_0[3] = {0.f,0.f,0.f},           b1_1[3] = {0.f,0.f,0.f};
        float b2_0[5] = {0.f,0.f,0.f,0.f,0.f},   b2_1[5] = {0.f,0.f,0.f,0.f,0.f};
        float b3_0[7] = {0.f,0.f,0.f,0.f,0.f,0.f,0.f};
        float b3_1[7] = {0.f,0.f,0.f,0.f,0.f,0.f,0.f};

        #pragma unroll
        for (int s = 0; s < 4; ++s) {
            const unsigned int* ts = tb + s * 32;   // LDS, uniform addr -> broadcast
            #pragma unroll
            for (int n = 0; n < 8; ++n) {
                float tv = tval(ts, n);
                float2 wv = Wl[(s*8+n)*64 + lane];
                aa0_0 = fmaf(wv.x, tv, aa0_0);
                aa0_1 = fmaf(wv.y, tv, aa0_1);
            }
            #pragma unroll
            for (int n = 0; n < 6; ++n) {
                float2 wv = Wl[(32 + s*6+n)*64 + lane];
                #pragma unroll
                for (int m = 0; m < 3; ++m) {
                    float tv = tval(ts, 8 + n*3 + m);
                    b1_0[m] = fmaf(wv.x, tv, b1_0[m]);
                    b1_1[m] = fmaf(wv.y, tv, b1_1[m]);
                }
            }
            #pragma unroll
            for (int n = 0; n < 4; ++n) {
                float2 wv = Wl[(56 + s*4+n)*64 + lane];
                #pragma unroll
                for (int m = 0; m < 5; ++m) {
                    float tv = tval(ts, 28 + n*5 + m);
                    b2_0[m] = fmaf(wv.x, tv, b2_0[m]);
                    b2_1[m] = fmaf(wv.y, tv, b2_1[m]);
                }
            }
            #pragma unroll
            for (int n = 0; n < 2; ++n) {
                float2 wv = Wl[(72 + s*2+n)*64 + lane];
                #pragma unroll
                for (int m = 0; m < 7; ++m) {
                    float tv = tval(ts, 48 + n*7 + m);
                    b3_0[m] = fmaf(wv.x, tv, b3_0[m]);
                    b3_1[m] = fmaf(wv.y, tv, b3_1[m]);
                }
            }
        }

        float Bj0 = aa0_0 * aa0_0;
        float Bj1 = aa0_1 * aa0_1;
        Bj0 += (b1_0[0]*b1_0[0] + b1_0[1]*b1_0[1] + b1_0[2]*b1_0[2]) * 0.57735026918962576f;
        Bj1 += (b1_1[0]*b1_1[0] + b1_1[1]*b1_1[1] + b1_1[2]*b1_1[2]) * 0.57735026918962576f;
        {
            float s0 = 0.f, s1v = 0.f;
            #pragma unroll
            for (int m = 0; m < 5; ++m) { s0 = fmaf(b2_0[m], b2_0[m], s0); s1v = fmaf(b2_1[m], b2_1[m], s1v); }
            Bj0 += s0 * 0.44721359549995794f;
            Bj1 += s1v * 0.44721359549995794f;
        }
        {
            float s0 = 0.f, s1v = 0.f;
            #pragma unroll
            for (int m = 0; m < 7; ++m) { s0 = fmaf(b3_0[m], b3_0[m], s0); s1v = fmaf(b3_1[m], b3_1[m], s1v); }
            Bj0 += s0 * 0.37796447300922725f;
            Bj1 += s1v * 0.37796447300922725f;
        }

        const int sp = species[atom];
        float v = Bj0 * Bj0 * emb2[sp*128 + lane] * w_out[lane]
                + Bj1 * Bj1 * emb2[sp*128 + lane + 64] * w_out[lane + 64];

        #pragma unroll
        for (int o = 32; o > 0; o >>= 1) v += __shfl_down(v, o, 64);
        if (lane == 0)
            atomicAdd(&sacc[batch_seg[atom]], fmaf(v, scal, comp_weights[sp]));
    }

    __syncthreads();
    if (tid < 128) {
        float p = sacc[tid];
        if (p != 0.0f) atomicAdd(&out[tid], p);
    }
}

extern "C" void kernel_launch(void* const* d_in, const int* in_sizes, int n_in,
                              void* d_out, int out_size, void* d_ws, size_t ws_size,
                              hipStream_t stream)
{
    const float* pos  = (const float*)d_in[0];
    const float* emb  = (const float*)d_in[1];
    const float* wr0  = (const float*)d_in[2];
    const float* wm0  = (const float*)d_in[3];
    const float* wr1  = (const float*)d_in[4];
    const float* wm1  = (const float*)d_in[5];
    const float* wr2  = (const float*)d_in[6];
    const float* wm2  = (const float*)d_in[7];
    const float* wr3  = (const float*)d_in[8];
    const float* wm3  = (const float*)d_in[9];
    const float* emb2 = (const float*)d_in[10];
    const float* wout = (const float*)d_in[11];
    const float* cw   = (const float*)d_in[12];
    const float* scal = (const float*)d_in[13];
    const int* species   = (const int*)d_in[14];
    const int* senders   = (const int*)d_in[15];
    const int* receivers = (const int*)d_in[16];
    const int* batch_seg = (const int*)d_in[17];

    int* counts    = (int*)d_ws;                  // 40064
    int* offsets   = counts + 40064;              // 40064 (block-local sums)
    int* rank      = offsets + 40064;             // 200000
    int* blocksums = rank + 200000;               // 64
    unsigned int* csr = (unsigned int*)(blocksums + 64); // 200000
    float* W2p     = (float*)(csr + 200000);      // 10240 floats
    unsigned int* Tb = (unsigned int*)(W2p + 10240); // 10000*128 uints = 5.12 MB

    zero_kernel<<<SCAN_BLOCKS, 1024, 0, stream>>>(counts, (float*)d_out, out_size);
    prep_count_kernel<<<40 + (NEDGES + 255)/256, 256, 0, stream>>>(
        emb, wm0, wm1, wm2, wm3, W2p, receivers, senders, species, counts, rank);
    scan1_kernel<<<SCAN_BLOCKS, 1024, 0, stream>>>(counts, offsets, blocksums);
    scatter_kernel<<<(NEDGES + 255)/256, 256, 0, stream>>>(
        receivers, senders, species, offsets, blocksums, rank, csr);
    edge_tbuild_kernel<<<NATOMS/16, 256, 0, stream>>>(
        pos, wr0, wr1, wr2, wr3, csr, offsets, blocksums, Tb);
    mix_kernel<<<250, 512, 0, stream>>>(
        Tb, W2p, emb2, wout, cw, scal, species, batch_seg, (float*)d_out);
}